// Round 12
// baseline (156.820 us; speedup 1.0000x reference)
//
#include <hip/hip_runtime.h>
#include <hip/hip_bf16.h>

// B=8, T=1024, D=512, H=8, DH=64, VS=512
typedef __bf16 bf16;
typedef __bf16 bf16x8 __attribute__((ext_vector_type(8)));
typedef __bf16 bf16x4 __attribute__((ext_vector_type(4)));
typedef float f32x4 __attribute__((ext_vector_type(4)));

#define NEGBIG (-3.0e38f)

__device__ inline f32x4 mfma16(bf16x8 a, bf16x8 b, f32x4 c) {
    return __builtin_amdgcn_mfma_f32_16x16x32_bf16(a, b, c, 0, 0, 0);
}
__device__ inline bf16x8 ld8(const bf16* p) { return *reinterpret_cast<const bf16x8*>(p); }
__device__ inline f32x4 ldf4(const float* p) { return *reinterpret_cast<const f32x4*>(p); }

// DPP row (16-lane) rotate: pure-VALU cross-lane, no LDS round-trip
template<int CTRL>
__device__ inline float rowror(float x) {
    int xi = __builtin_bit_cast(int, x);
    int yi = __builtin_amdgcn_update_dpp(xi, xi, CTRL, 0xF, 0xF, false);
    return __builtin_bit_cast(float, yi);
}
__device__ inline float rowmax16(float x) {
    x = fmaxf(x, rowror<0x121>(x));
    x = fmaxf(x, rowror<0x122>(x));
    x = fmaxf(x, rowror<0x124>(x));
    x = fmaxf(x, rowror<0x128>(x));
    return x;
}
__device__ inline float rowsum16(float x) {
    x += rowror<0x121>(x);
    x += rowror<0x122>(x);
    x += rowror<0x124>(x);
    x += rowror<0x128>(x);
    return x;
}

// ---------------- fused tables: pe (swizzled) + vb + wcvt x3 ----------------
// blocks [0,512): pe; [512,576): vb; [576,768): wcvt
__global__ __launch_bounds__(256) void tables_kernel(const float* __restrict__ v_bias,
                                                     const float* __restrict__ W0, const float* __restrict__ W1,
                                                     const float* __restrict__ W2, bf16* __restrict__ pe_b,
                                                     float* __restrict__ vb, bf16* __restrict__ T0,
                                                     bf16* __restrict__ T1, bf16* __restrict__ T2) {
    __shared__ float tile[64][65];
    int bid = blockIdx.x;
    if (bid < 512) {
        int g = bid * 256 + threadIdx.x;       // 131072 = 2048 l x 64 d
        int l = g >> 6, d = g & 63;
        float pos = (float)(l - 1024);
        float dv = __expf(-(float)(d & 31) * 0.29710775393471563f);   // ln(10000)/31
        float ang = pos * dv;
        float v = (d < 32) ? sinf(ang) : cosf(ang);
        int idx = (((l >> 4) << 1) + (d >> 5)) * 512 + (((d >> 3) & 3) * 16 + (l & 15)) * 8 + (d & 7);
        pe_b[idx] = (bf16)v;
    } else if (bid < 576) {
        int t = (bid - 512) * 256 + threadIdx.x;   // h*2048 + l
        int h = t >> 11, l = t & 2047;
        float pos = (float)(l - 1024);
        float s = 0.f;
        #pragma unroll 4
        for (int d = 0; d < 32; d++) {
            float dv = __expf(-(float)d * 0.29710775393471563f);
            float ang = pos * dv;
            s += v_bias[h * 64 + d] * sinf(ang) + v_bias[h * 64 + 32 + d] * cosf(ang);
        }
        vb[t] = s;
    } else {
        int wb = bid - 576;
        int which = wb >> 6, bidx = wb & 63;
        const float* W = which == 0 ? W0 : which == 1 ? W1 : W2;
        bf16* Wt = which == 0 ? T0 : which == 1 ? T1 : T2;
        int tx = bidx & 7, ty = bidx >> 3;
        int lane = threadIdx.x & 63, w = threadIdx.x >> 6;
        #pragma unroll
        for (int i = 0; i < 16; i++) {
            int k = ty * 64 + w * 16 + i;
            tile[w * 16 + i][lane] = W[k * 512 + tx * 64 + lane];
        }
        __syncthreads();
        #pragma unroll
        for (int i = 0; i < 16; i++) {
            int n = tx * 64 + w * 16 + i;
            Wt[n * 512 + ty * 64 + lane] = (bf16)tile[lane][w * 16 + i];
        }
    }
}

// ---------------- key convert: fp32 [b][t][h*64+dh] -> fragment-swizzled bf16 ----------------
__global__ void kcvt_kernel(const float* __restrict__ kin, bf16* __restrict__ kw) {
    int i = (blockIdx.x * 256 + threadIdx.x) * 4;
    f32x4 v = ldf4(kin + i);
    int dh = i & 63, hh = (i >> 6) & 7, t = (i >> 9) & 1023, b = i >> 19;
    int bh = (b << 3) + hh;
    bf16x4 o;
    #pragma unroll
    for (int e = 0; e < 4; e++) o[e] = (bf16)v[e];
    int blk = ((bh << 6) + (t >> 4)) * 2 + (dh >> 5);
    int off = (((dh >> 3) & 3) * 16 + (t & 15)) * 8 + (dh & 7);
    *reinterpret_cast<bf16x4*>(kw + blk * 512 + off) = o;
}

// ---------------- merged q+v proj: 64x64/BK32, pre-transposed bf16 W ----------------
// blockIdx.z==0: query -> q_ws (linear [bh][t][dh]); z==1: value -> v_ws (fragment-swizzled V^T)
__global__ __launch_bounds__(256) void proj_qv(const float* __restrict__ Q, const float* __restrict__ V,
                                               const bf16* __restrict__ WtQ, const bf16* __restrict__ WtV,
                                               const float* __restrict__ bq, const float* __restrict__ bv,
                                               bf16* __restrict__ q_ws, bf16* __restrict__ v_ws) {
    __shared__ bf16 As[64][40];
    __shared__ bf16 Bs[64][40];
    int isv = blockIdx.z;
    const float* A = isv ? V : Q;
    const bf16* Wt = isv ? WtV : WtQ;
    const float* bias = isv ? bv : bq;
    int row0 = blockIdx.x * 64, n0 = blockIdx.y * 64;
    int tid = threadIdx.x, lane = tid & 63, w = tid >> 6, lg = lane >> 4, lr = lane & 15;
    int wm = (w >> 1) * 32, wn = (w & 1) * 32;
    f32x4 acc[2][2] = {};
    for (int k0 = 0; k0 < 512; k0 += 32) {
        int r = tid >> 2, kq = (tid & 3) * 8;
        f32x4 a0 = ldf4(A + (row0 + r) * 512 + k0 + kq);
        f32x4 a1 = ldf4(A + (row0 + r) * 512 + k0 + kq + 4);
        bf16x8 av;
        #pragma unroll
        for (int e = 0; e < 4; e++) { av[e] = (bf16)a0[e]; av[4 + e] = (bf16)a1[e]; }
        bf16x8 bv8 = ld8(Wt + (n0 + r) * 512 + k0 + kq);
        __syncthreads();
        *reinterpret_cast<bf16x8*>(&As[r][kq]) = av;
        *reinterpret_cast<bf16x8*>(&Bs[r][kq]) = bv8;
        __syncthreads();
        bf16x8 aa0 = ld8(&As[wm + lr][lg * 8]);
        bf16x8 aa1 = ld8(&As[wm + 16 + lr][lg * 8]);
        bf16x8 bb0 = ld8(&Bs[wn + lr][lg * 8]);
        bf16x8 bb1 = ld8(&Bs[wn + 16 + lr][lg * 8]);
        acc[0][0] = mfma16(aa0, bb0, acc[0][0]);
        acc[0][1] = mfma16(aa0, bb1, acc[0][1]);
        acc[1][0] = mfma16(aa1, bb0, acc[1][0]);
        acc[1][1] = mfma16(aa1, bb1, acc[1][1]);
    }
    #pragma unroll
    for (int mi = 0; mi < 2; mi++)
    #pragma unroll
    for (int ni = 0; ni < 2; ni++) {
        int rowb = row0 + wm + mi * 16 + lg * 4;
        int col = n0 + wn + ni * 16 + lr;
        int b = rowb >> 10, t = rowb & 1023, hh = col >> 6, dh = col & 63;
        int bh = (b << 3) + hh;
        if (isv) {
            int blk = (((bh << 4) + (t >> 6)) * 2 + ((t >> 5) & 1)) * 4 + (dh >> 4);
            int off = (((t >> 3) & 3) * 16 + (dh & 15)) * 8 + (t & 7);
            bf16x4 o4;
            #pragma unroll
            for (int rr = 0; rr < 4; rr++) o4[rr] = (bf16)((float)acc[mi][ni][rr] + bias[col]);
            *reinterpret_cast<bf16x4*>(v_ws + blk * 512 + off) = o4;
        } else {
            #pragma unroll
            for (int rr = 0; rr < 4; rr++) {
                float v = (float)acc[mi][ni][rr] + bias[col];
                q_ws[((bh << 10) + t + rr) * 64 + dh] = (bf16)v;
            }
        }
    }
}

// ---------------- output proj: 64x64/BK32, bf16 A (x_ws), fp32 out ----------------
__global__ __launch_bounds__(256) void proj_o(const bf16* __restrict__ Ap, const bf16* __restrict__ Wt,
                                              const float* __restrict__ bias, float* __restrict__ outp) {
    __shared__ bf16 As[64][40];
    __shared__ bf16 Bs[64][40];
    int row0 = blockIdx.x * 64, n0 = blockIdx.y * 64;
    int tid = threadIdx.x, lane = tid & 63, w = tid >> 6, lg = lane >> 4, lr = lane & 15;
    int wm = (w >> 1) * 32, wn = (w & 1) * 32;
    f32x4 acc[2][2] = {};
    for (int k0 = 0; k0 < 512; k0 += 32) {
        int r = tid >> 2, kq = (tid & 3) * 8;
        bf16x8 av = ld8(Ap + (row0 + r) * 512 + k0 + kq);
        bf16x8 bv = ld8(Wt + (n0 + r) * 512 + k0 + kq);
        __syncthreads();
        *reinterpret_cast<bf16x8*>(&As[r][kq]) = av;
        *reinterpret_cast<bf16x8*>(&Bs[r][kq]) = bv;
        __syncthreads();
        bf16x8 a0 = ld8(&As[wm + lr][lg * 8]);
        bf16x8 a1 = ld8(&As[wm + 16 + lr][lg * 8]);
        bf16x8 b0 = ld8(&Bs[wn + lr][lg * 8]);
        bf16x8 b1 = ld8(&Bs[wn + 16 + lr][lg * 8]);
        acc[0][0] = mfma16(a0, b0, acc[0][0]);
        acc[0][1] = mfma16(a0, b1, acc[0][1]);
        acc[1][0] = mfma16(a1, b0, acc[1][0]);
        acc[1][1] = mfma16(a1, b1, acc[1][1]);
    }
    #pragma unroll
    for (int mi = 0; mi < 2; mi++)
    #pragma unroll
    for (int ni = 0; ni < 2; ni++) {
        int rowb = row0 + wm + mi * 16 + lg * 4;
        int col = n0 + wn + ni * 16 + lr;
        #pragma unroll
        for (int rr = 0; rr < 4; rr++)
            outp[(rowb + rr) * 512 + col] = (float)acc[mi][ni][rr] + bias[col];
    }
}

// ---------------- fused TENER attention: split-j wave pairs + K register prefetch ----------------
// grid (64 bh, 32 qt-pairs), block 256 = 4 waves. (256,4): VGPR cap 128; do not tighten
// (r5/r10: (256,8)/(256,6) both spill).
__global__ __launch_bounds__(256, 4) void tener_attn(const bf16* __restrict__ qw, const bf16* __restrict__ kw,
                                                     const bf16* __restrict__ vt, const int* __restrict__ mask,
                                                     const bf16* __restrict__ peb, const float* __restrict__ vb,
                                                     bf16* __restrict__ xw) {
    __shared__ bf16 Pl[4][16][76];
    __shared__ float Mo[4][16], Do[4][16];
    __shared__ float Oo[2][16][65];
    int bh = blockIdx.x, b = bh >> 3, h = bh & 7;
    int tid = threadIdx.x, w = tid >> 6, lane = tid & 63, lg = lane >> 4, lr = lane & 15;
    int rbase = (blockIdx.y * 2 + (w >> 1)) * 16;
    int jh = w & 1;

    const float* vbh  = vb + (h << 11);
    const int* mkb    = mask + (b << 10);

    bf16x8 aq0 = ld8(qw + ((bh << 10) + rbase + lr) * 64 + lg * 8);
    bf16x8 aq1 = ld8(qw + ((bh << 10) + rbase + lr) * 64 + 32 + lg * 8);

    f32x4 o[4] = {};
    float m_[4], d_[4];
    #pragma unroll
    for (int r = 0; r < 4; r++) { m_[r] = NEGBIG; d_[r] = 0.f; }

    // prefetch tile 0's K fragments
    bf16x8 kf[8];
    {
        int kblk = (bh << 6) + ((jh * 512) >> 4);
        #pragma unroll
        for (int nt = 0; nt < 4; nt++) {
            const bf16* kp = kw + ((kblk + nt) << 1) * 512 + lane * 8;
            kf[2 * nt] = ld8(kp);
            kf[2 * nt + 1] = ld8(kp + 512);
        }
    }

    for (int tt = 0; tt < 8; tt++) {
        __builtin_amdgcn_sched_barrier(0x7F);   // DS may not cross

        int j0 = jh * 512 + tt * 64;
        int L0 = 1024 + j0 - rbase;

        // S = Q.K^T from prefetched registers
        f32x4 s[4];
        #pragma unroll
        for (int nt = 0; nt < 4; nt++) {
            f32x4 acc = {};
            acc = mfma16(aq0, kf[2 * nt], acc);
            acc = mfma16(aq1, kf[2 * nt + 1], acc);
            s[nt] = acc;
        }

        // issue next tile's K loads now: latency hides under rel + softmax
        bf16x8 kn[8];
        if (tt < 7) {
            int kblk1 = (bh << 6) + ((j0 + 64) >> 4);
            #pragma unroll
            for (int nt = 0; nt < 4; nt++) {
                const bf16* kp = kw + ((kblk1 + nt) << 1) * 512 + lane * 8;
                kn[2 * nt] = ld8(kp);
                kn[2 * nt + 1] = ld8(kp + 512);
            }
        }

        // R band + vb folded — coalesced pe fragment loads
        f32x4 Rg[5];
        int lb = (L0 - 16) >> 4;
        #pragma unroll
        for (int ut = 0; ut < 5; ut++) {
            const bf16* pp = peb + (((lb + ut) << 1)) * 512 + lane * 8;
            f32x4 acc = {};
            acc = mfma16(aq0, ld8(pp), acc);
            acc = mfma16(aq1, ld8(pp + 512), acc);
            float vbv = vbh[L0 - 16 + ut * 16 + lr];
            #pragma unroll
            for (int r = 0; r < 4; r++) acc[r] += vbv;
            Rg[ut] = acc;
        }

        int mk[4];
        #pragma unroll
        for (int nt = 0; nt < 4; nt++) mk[nt] = mkb[j0 + nt * 16 + lr];

        // online softmax; rel via in-register shuffles, reduces via DPP
        #pragma unroll
        for (int r = 0; r < 4; r++) {
            int rl = 4 * lg + r;
            int dlt = lr - rl;
            int src = (lg << 4) | (dlt & 15);
            float sh[5];
            #pragma unroll
            for (int ut = 0; ut < 5; ut++) sh[ut] = __shfl(Rg[ut][r], src, 64);
            float sv[4];
            #pragma unroll
            for (int nt = 0; nt < 4; nt++) {
                float rel = (dlt >= 0) ? sh[nt + 1] : sh[nt];
                sv[nt] = mk[nt] ? (float)s[nt][r] + rel : NEGBIG;
            }
            float mx = fmaxf(fmaxf(sv[0], sv[1]), fmaxf(sv[2], sv[3]));
            mx = rowmax16(mx);
            float nm = fmaxf(m_[r], mx);
            float sc = __expf(m_[r] - nm);
            float p[4], rs = 0.f;
            #pragma unroll
            for (int nt = 0; nt < 4; nt++) {
                p[nt] = mk[nt] ? __expf(sv[nt] - nm) : 0.f;
                rs += p[nt];
            }
            rs = rowsum16(rs);
            d_[r] = d_[r] * sc + rs;
            m_[r] = nm;
            #pragma unroll
            for (int dt = 0; dt < 4; dt++) o[dt][r] *= sc;
            #pragma unroll
            for (int nt = 0; nt < 4; nt++) Pl[w][rl][nt * 16 + lr] = (bf16)p[nt];
        }

        __builtin_amdgcn_sched_barrier(0x7F);   // DS may not cross (Pl WAR/RAW fence)

        // O += P.V — V^T fragment loads fully coalesced
        int vblk0 = ((((bh << 4) + (j0 >> 6)) << 1)) << 2;
        #pragma unroll
        for (int ks = 0; ks < 2; ks++) {
            bf16x8 ap = ld8(&Pl[w][lr][ks * 32 + lg * 8]);
            #pragma unroll
            for (int dt = 0; dt < 4; dt++) {
                const bf16* vp = vt + (vblk0 + (ks << 2) + dt) * 512 + lane * 8;
                o[dt] = mfma16(ap, ld8(vp), o[dt]);
            }
        }

        if (tt < 7) {
            #pragma unroll
            for (int e = 0; e < 8; e++) kf[e] = kn[e];
        }
    }

    // pair-merge: odd wave publishes partials, even wave combines + writes
    if (w & 1) {
        #pragma unroll
        for (int dt = 0; dt < 4; dt++)
        #pragma unroll
        for (int r = 0; r < 4; r++)
            Oo[w >> 1][4 * lg + r][dt * 16 + lr] = o[dt][r];
        if (lr == 0) {
            #pragma unroll
            for (int r = 0; r < 4; r++) { Mo[w][4 * lg + r] = m_[r]; Do[w][4 * lg + r] = d_[r]; }
        }
    }
    __syncthreads();
    if (!(w & 1)) {
        #pragma unroll
        for (int r = 0; r < 4; r++) {
            int rl = 4 * lg + r;
            float m1 = Mo[w | 1][rl], d1 = Do[w | 1][rl];
            float m = fmaxf(m_[r], m1);
            float a0 = __expf(m_[r] - m), a1 = __expf(m1 - m);
            float dd = d_[r] * a0 + d1 * a1;
            float inv = dd > 0.f ? 1.f / dd : 0.f;
            int row = rbase + rl;
            #pragma unroll
            for (int dt = 0; dt < 4; dt++) {
                float v = (o[dt][r] * a0 + Oo[w >> 1][rl][dt * 16 + lr] * a1) * inv;
                xw[(((b << 10) + row) << 9) + (h << 6) + dt * 16 + lr] = (bf16)v;
            }
        }
    }
}

extern "C" void kernel_launch(void* const* d_in, const int* in_sizes, int n_in,
                              void* d_out, int out_size, void* d_ws, size_t ws_size,
                              hipStream_t stream) {
    const float* query  = (const float*)d_in[0];
    const float* key_in = (const float*)d_in[1];
    const float* value  = (const float*)d_in[2];
    const int*   mask   = (const int*)d_in[3];
    const float* Wq     = (const float*)d_in[4];
    const float* bq     = (const float*)d_in[5];
    const float* Wv     = (const float*)d_in[6];
    const float* bv     = (const float*)d_in[7];
    const float* Wo     = (const float*)d_in[8];
    const float* bo     = (const float*)d_in[9];
    const float* v_bias = (const float*)d_in[10];

    char* ws = (char*)d_ws;
    bf16*  pe_b = (bf16*)(ws);                           // 256 KB (swizzled)
    float* vb   = (float*)(ws + 262144);                 // 64 KB
    bf16*  q_ws = (bf16*)(ws + 327680);                  // 8 MB  [bh][t][dh]
    bf16*  v_ws = (bf16*)(ws + 327680 + 8388608);        // 8 MB  V^T fragment-swizzled
    bf16*  x_ws = (bf16*)(ws + 327680 + 16777216);       // 8 MB  [b*t][512]
    bf16*  wt_q = (bf16*)(ws + 327680 + 25165824);       // 512 KB  Wq^T bf16
    bf16*  wt_v = (bf16*)(ws + 327680 + 25690112);       // 512 KB  Wv^T bf16
    bf16*  wt_o = (bf16*)(ws + 327680 + 26214400);       // 512 KB  Wo^T bf16
    // k_ws lives in d_out's first 8 MB; consumed before proj_o writes d_out.
    bf16*  k_ws = (bf16*)d_out;

    tables_kernel<<<768, 256, 0, stream>>>(v_bias, Wq, Wv, Wo, pe_b, vb, wt_q, wt_v, wt_o);
    kcvt_kernel<<<4096, 256, 0, stream>>>(key_in, k_ws);
    proj_qv<<<dim3(128, 8, 2), 256, 0, stream>>>(query, value, wt_q, wt_v, bq, bv, q_ws, v_ws);
    tener_attn<<<dim3(64, 32), 256, 0, stream>>>(q_ws, k_ws, v_ws, mask, pe_b, vb, x_ws);
    proj_o<<<dim3(128, 8), 256, 0, stream>>>(x_ws, wt_o, bo, (float*)d_out);
}

// Round 13
// 133.056 us; speedup vs baseline: 1.1786x; 1.1786x over previous
//
#include <hip/hip_runtime.h>
#include <hip/hip_bf16.h>

// B=8, T=1024, D=512, H=8, DH=64, VS=512
typedef __bf16 bf16;
typedef __bf16 bf16x8 __attribute__((ext_vector_type(8)));
typedef __bf16 bf16x4 __attribute__((ext_vector_type(4)));
typedef float f32x4 __attribute__((ext_vector_type(4)));

#define NEGBIG (-3.0e38f)

__device__ inline f32x4 mfma16(bf16x8 a, bf16x8 b, f32x4 c) {
    return __builtin_amdgcn_mfma_f32_16x16x32_bf16(a, b, c, 0, 0, 0);
}
__device__ inline bf16x8 ld8(const bf16* p) { return *reinterpret_cast<const bf16x8*>(p); }
__device__ inline f32x4 ldf4(const float* p) { return *reinterpret_cast<const f32x4*>(p); }

// DPP row (16-lane) rotate: pure-VALU cross-lane, no LDS round-trip
template<int CTRL>
__device__ inline float rowror(float x) {
    int xi = __builtin_bit_cast(int, x);
    int yi = __builtin_amdgcn_update_dpp(xi, xi, CTRL, 0xF, 0xF, false);
    return __builtin_bit_cast(float, yi);
}
__device__ inline float rowmax16(float x) {
    x = fmaxf(x, rowror<0x121>(x));
    x = fmaxf(x, rowror<0x122>(x));
    x = fmaxf(x, rowror<0x124>(x));
    x = fmaxf(x, rowror<0x128>(x));
    return x;
}
__device__ inline float rowsum16(float x) {
    x += rowror<0x121>(x);
    x += rowror<0x122>(x);
    x += rowror<0x124>(x);
    x += rowror<0x128>(x);
    return x;
}

// ---------------- fused tables: pe (swizzled) + vb + wcvt x3 ----------------
// blocks [0,512): pe; [512,576): vb; [576,768): wcvt
__global__ __launch_bounds__(256) void tables_kernel(const float* __restrict__ v_bias,
                                                     const float* __restrict__ W0, const float* __restrict__ W1,
                                                     const float* __restrict__ W2, bf16* __restrict__ pe_b,
                                                     float* __restrict__ vb, bf16* __restrict__ T0,
                                                     bf16* __restrict__ T1, bf16* __restrict__ T2) {
    __shared__ float tile[64][65];
    int bid = blockIdx.x;
    if (bid < 512) {
        int g = bid * 256 + threadIdx.x;       // 131072 = 2048 l x 64 d
        int l = g >> 6, d = g & 63;
        float pos = (float)(l - 1024);
        float dv = __expf(-(float)(d & 31) * 0.29710775393471563f);   // ln(10000)/31
        float ang = pos * dv;
        float v = (d < 32) ? sinf(ang) : cosf(ang);
        int idx = (((l >> 4) << 1) + (d >> 5)) * 512 + (((d >> 3) & 3) * 16 + (l & 15)) * 8 + (d & 7);
        pe_b[idx] = (bf16)v;
    } else if (bid < 576) {
        int t = (bid - 512) * 256 + threadIdx.x;   // h*2048 + l
        int h = t >> 11, l = t & 2047;
        float pos = (float)(l - 1024);
        float s = 0.f;
        #pragma unroll 4
        for (int d = 0; d < 32; d++) {
            float dv = __expf(-(float)d * 0.29710775393471563f);
            float ang = pos * dv;
            s += v_bias[h * 64 + d] * sinf(ang) + v_bias[h * 64 + 32 + d] * cosf(ang);
        }
        vb[t] = s;
    } else {
        int wb = bid - 576;
        int which = wb >> 6, bidx = wb & 63;
        const float* W = which == 0 ? W0 : which == 1 ? W1 : W2;
        bf16* Wt = which == 0 ? T0 : which == 1 ? T1 : T2;
        int tx = bidx & 7, ty = bidx >> 3;
        int lane = threadIdx.x & 63, w = threadIdx.x >> 6;
        #pragma unroll
        for (int i = 0; i < 16; i++) {
            int k = ty * 64 + w * 16 + i;
            tile[w * 16 + i][lane] = W[k * 512 + tx * 64 + lane];
        }
        __syncthreads();
        #pragma unroll
        for (int i = 0; i < 16; i++) {
            int n = tx * 64 + w * 16 + i;
            Wt[n * 512 + ty * 64 + lane] = (bf16)tile[lane][w * 16 + i];
        }
    }
}

// ---------------- key convert: fp32 [b][t][h*64+dh] -> fragment-swizzled bf16 ----------------
__global__ void kcvt_kernel(const float* __restrict__ kin, bf16* __restrict__ kw) {
    int i = (blockIdx.x * 256 + threadIdx.x) * 4;
    f32x4 v = ldf4(kin + i);
    int dh = i & 63, hh = (i >> 6) & 7, t = (i >> 9) & 1023, b = i >> 19;
    int bh = (b << 3) + hh;
    bf16x4 o;
    #pragma unroll
    for (int e = 0; e < 4; e++) o[e] = (bf16)v[e];
    int blk = ((bh << 6) + (t >> 4)) * 2 + (dh >> 5);
    int off = (((dh >> 3) & 3) * 16 + (t & 15)) * 8 + (dh & 7);
    *reinterpret_cast<bf16x4*>(kw + blk * 512 + off) = o;
}

// ---------------- merged q+v proj: 64x64/BK32, pre-transposed bf16 W ----------------
// blockIdx.z==0: query -> q_ws (linear [bh][t][dh]); z==1: value -> v_ws (fragment-swizzled V^T)
__global__ __launch_bounds__(256) void proj_qv(const float* __restrict__ Q, const float* __restrict__ V,
                                               const bf16* __restrict__ WtQ, const bf16* __restrict__ WtV,
                                               const float* __restrict__ bq, const float* __restrict__ bv,
                                               bf16* __restrict__ q_ws, bf16* __restrict__ v_ws) {
    __shared__ bf16 As[64][40];
    __shared__ bf16 Bs[64][40];
    int isv = blockIdx.z;
    const float* A = isv ? V : Q;
    const bf16* Wt = isv ? WtV : WtQ;
    const float* bias = isv ? bv : bq;
    int row0 = blockIdx.x * 64, n0 = blockIdx.y * 64;
    int tid = threadIdx.x, lane = tid & 63, w = tid >> 6, lg = lane >> 4, lr = lane & 15;
    int wm = (w >> 1) * 32, wn = (w & 1) * 32;
    f32x4 acc[2][2] = {};
    for (int k0 = 0; k0 < 512; k0 += 32) {
        int r = tid >> 2, kq = (tid & 3) * 8;
        f32x4 a0 = ldf4(A + (row0 + r) * 512 + k0 + kq);
        f32x4 a1 = ldf4(A + (row0 + r) * 512 + k0 + kq + 4);
        bf16x8 av;
        #pragma unroll
        for (int e = 0; e < 4; e++) { av[e] = (bf16)a0[e]; av[4 + e] = (bf16)a1[e]; }
        bf16x8 bv8 = ld8(Wt + (n0 + r) * 512 + k0 + kq);
        __syncthreads();
        *reinterpret_cast<bf16x8*>(&As[r][kq]) = av;
        *reinterpret_cast<bf16x8*>(&Bs[r][kq]) = bv8;
        __syncthreads();
        bf16x8 aa0 = ld8(&As[wm + lr][lg * 8]);
        bf16x8 aa1 = ld8(&As[wm + 16 + lr][lg * 8]);
        bf16x8 bb0 = ld8(&Bs[wn + lr][lg * 8]);
        bf16x8 bb1 = ld8(&Bs[wn + 16 + lr][lg * 8]);
        acc[0][0] = mfma16(aa0, bb0, acc[0][0]);
        acc[0][1] = mfma16(aa0, bb1, acc[0][1]);
        acc[1][0] = mfma16(aa1, bb0, acc[1][0]);
        acc[1][1] = mfma16(aa1, bb1, acc[1][1]);
    }
    #pragma unroll
    for (int mi = 0; mi < 2; mi++)
    #pragma unroll
    for (int ni = 0; ni < 2; ni++) {
        int rowb = row0 + wm + mi * 16 + lg * 4;
        int col = n0 + wn + ni * 16 + lr;
        int b = rowb >> 10, t = rowb & 1023, hh = col >> 6, dh = col & 63;
        int bh = (b << 3) + hh;
        if (isv) {
            int blk = (((bh << 4) + (t >> 6)) * 2 + ((t >> 5) & 1)) * 4 + (dh >> 4);
            int off = (((t >> 3) & 3) * 16 + (dh & 15)) * 8 + (t & 7);
            bf16x4 o4;
            #pragma unroll
            for (int rr = 0; rr < 4; rr++) o4[rr] = (bf16)((float)acc[mi][ni][rr] + bias[col]);
            *reinterpret_cast<bf16x4*>(v_ws + blk * 512 + off) = o4;
        } else {
            #pragma unroll
            for (int rr = 0; rr < 4; rr++) {
                float v = (float)acc[mi][ni][rr] + bias[col];
                q_ws[((bh << 10) + t + rr) * 64 + dh] = (bf16)v;
            }
        }
    }
}

// ---------------- output proj: 64x64/BK32, bf16 A (x_ws), fp32 out ----------------
__global__ __launch_bounds__(256) void proj_o(const bf16* __restrict__ Ap, const bf16* __restrict__ Wt,
                                              const float* __restrict__ bias, float* __restrict__ outp) {
    __shared__ bf16 As[64][40];
    __shared__ bf16 Bs[64][40];
    int row0 = blockIdx.x * 64, n0 = blockIdx.y * 64;
    int tid = threadIdx.x, lane = tid & 63, w = tid >> 6, lg = lane >> 4, lr = lane & 15;
    int wm = (w >> 1) * 32, wn = (w & 1) * 32;
    f32x4 acc[2][2] = {};
    for (int k0 = 0; k0 < 512; k0 += 32) {
        int r = tid >> 2, kq = (tid & 3) * 8;
        bf16x8 av = ld8(Ap + (row0 + r) * 512 + k0 + kq);
        bf16x8 bv = ld8(Wt + (n0 + r) * 512 + k0 + kq);
        __syncthreads();
        *reinterpret_cast<bf16x8*>(&As[r][kq]) = av;
        *reinterpret_cast<bf16x8*>(&Bs[r][kq]) = bv;
        __syncthreads();
        bf16x8 a0 = ld8(&As[wm + lr][lg * 8]);
        bf16x8 a1 = ld8(&As[wm + 16 + lr][lg * 8]);
        bf16x8 b0 = ld8(&Bs[wn + lr][lg * 8]);
        bf16x8 b1 = ld8(&Bs[wn + 16 + lr][lg * 8]);
        acc[0][0] = mfma16(a0, b0, acc[0][0]);
        acc[0][1] = mfma16(a0, b1, acc[0][1]);
        acc[1][0] = mfma16(a1, b0, acc[1][0]);
        acc[1][1] = mfma16(a1, b1, acc[1][1]);
    }
    #pragma unroll
    for (int mi = 0; mi < 2; mi++)
    #pragma unroll
    for (int ni = 0; ni < 2; ni++) {
        int rowb = row0 + wm + mi * 16 + lg * 4;
        int col = n0 + wn + ni * 16 + lr;
        #pragma unroll
        for (int rr = 0; rr < 4; rr++)
            outp[(rowb + rr) * 512 + col] = (float)acc[mi][ni][rr] + bias[col];
    }
}

// ---------------- fused TENER attention (round-11 proven body, no prefetch) ----------------
// grid (64 bh, 32 qt-pairs), block 256 = 4 waves:
//   wave w -> q-tile (blockIdx.y*2 + (w>>1)), j-half (w&1). Pair merges at end.
// (256,4) measured-best: VGPR 56, no spill. Any extra live state (prefetch regs,
// r12) or tighter bounds (r5/r10) spills. Do not touch.
__global__ __launch_bounds__(256, 4) void tener_attn(const bf16* __restrict__ qw, const bf16* __restrict__ kw,
                                                     const bf16* __restrict__ vt, const int* __restrict__ mask,
                                                     const bf16* __restrict__ peb, const float* __restrict__ vb,
                                                     bf16* __restrict__ xw) {
    __shared__ bf16 Pl[4][16][76];     // per-wave P relayout
    __shared__ float Mo[4][16], Do[4][16];
    __shared__ float Oo[2][16][65];    // odd-wave partial O per pair
    int bh = blockIdx.x, b = bh >> 3, h = bh & 7;
    int tid = threadIdx.x, w = tid >> 6, lane = tid & 63, lg = lane >> 4, lr = lane & 15;
    int rbase = (blockIdx.y * 2 + (w >> 1)) * 16;
    int jh = w & 1;

    const float* vbh  = vb + (h << 11);
    const int* mkb    = mask + (b << 10);

    bf16x8 aq0 = ld8(qw + ((bh << 10) + rbase + lr) * 64 + lg * 8);
    bf16x8 aq1 = ld8(qw + ((bh << 10) + rbase + lr) * 64 + 32 + lg * 8);

    f32x4 o[4] = {};
    float m_[4], d_[4];
    #pragma unroll
    for (int r = 0; r < 4; r++) { m_[r] = NEGBIG; d_[r] = 0.f; }

    for (int tt = 0; tt < 8; tt++) {
        __builtin_amdgcn_sched_barrier(0x7F);   // DS may not cross

        int j0 = jh * 512 + tt * 64;
        int L0 = 1024 + j0 - rbase;

        // S = Q.K^T — fragment loads fully coalesced (base + lane*16B)
        f32x4 s[4];
        int kblk = (bh << 6) + (j0 >> 4);
        #pragma unroll
        for (int nt = 0; nt < 4; nt++) {
            const bf16* kp = kw + (((kblk + nt) << 1)) * 512 + lane * 8;
            f32x4 acc = {};
            acc = mfma16(aq0, ld8(kp), acc);
            acc = mfma16(aq1, ld8(kp + 512), acc);
            s[nt] = acc;
        }

        // R band + vb folded — coalesced pe fragment loads
        f32x4 Rg[5];
        int lb = (L0 - 16) >> 4;
        #pragma unroll
        for (int ut = 0; ut < 5; ut++) {
            const bf16* pp = peb + (((lb + ut) << 1)) * 512 + lane * 8;
            f32x4 acc = {};
            acc = mfma16(aq0, ld8(pp), acc);
            acc = mfma16(aq1, ld8(pp + 512), acc);
            float vbv = vbh[L0 - 16 + ut * 16 + lr];
            #pragma unroll
            for (int r = 0; r < 4; r++) acc[r] += vbv;
            Rg[ut] = acc;
        }

        int mk[4];
        #pragma unroll
        for (int nt = 0; nt < 4; nt++) mk[nt] = mkb[j0 + nt * 16 + lr];

        // online softmax; rel via in-register shuffles, reduces via DPP
        #pragma unroll
        for (int r = 0; r < 4; r++) {
            int rl = 4 * lg + r;
            int dlt = lr - rl;
            int src = (lg << 4) | (dlt & 15);
            float sh[5];
            #pragma unroll
            for (int ut = 0; ut < 5; ut++) sh[ut] = __shfl(Rg[ut][r], src, 64);
            float sv[4];
            #pragma unroll
            for (int nt = 0; nt < 4; nt++) {
                float rel = (dlt >= 0) ? sh[nt + 1] : sh[nt];
                sv[nt] = mk[nt] ? (float)s[nt][r] + rel : NEGBIG;
            }
            float mx = fmaxf(fmaxf(sv[0], sv[1]), fmaxf(sv[2], sv[3]));
            mx = rowmax16(mx);
            float nm = fmaxf(m_[r], mx);
            float sc = __expf(m_[r] - nm);
            float p[4], rs = 0.f;
            #pragma unroll
            for (int nt = 0; nt < 4; nt++) {
                p[nt] = mk[nt] ? __expf(sv[nt] - nm) : 0.f;
                rs += p[nt];
            }
            rs = rowsum16(rs);
            d_[r] = d_[r] * sc + rs;
            m_[r] = nm;
            #pragma unroll
            for (int dt = 0; dt < 4; dt++) o[dt][r] *= sc;
            #pragma unroll
            for (int nt = 0; nt < 4; nt++) Pl[w][rl][nt * 16 + lr] = (bf16)p[nt];
        }

        __builtin_amdgcn_sched_barrier(0x7F);   // DS may not cross (Pl WAR/RAW fence)

        // O += P.V — V^T fragment loads fully coalesced
        int vblk0 = ((((bh << 4) + (j0 >> 6)) << 1)) << 2;
        #pragma unroll
        for (int ks = 0; ks < 2; ks++) {
            bf16x8 ap = ld8(&Pl[w][lr][ks * 32 + lg * 8]);
            #pragma unroll
            for (int dt = 0; dt < 4; dt++) {
                const bf16* vp = vt + (vblk0 + (ks << 2) + dt) * 512 + lane * 8;
                o[dt] = mfma16(ap, ld8(vp), o[dt]);
            }
        }
    }

    // pair-merge: odd wave publishes partials, even wave combines + writes
    if (w & 1) {
        #pragma unroll
        for (int dt = 0; dt < 4; dt++)
        #pragma unroll
        for (int r = 0; r < 4; r++)
            Oo[w >> 1][4 * lg + r][dt * 16 + lr] = o[dt][r];
        if (lr == 0) {
            #pragma unroll
            for (int r = 0; r < 4; r++) { Mo[w][4 * lg + r] = m_[r]; Do[w][4 * lg + r] = d_[r]; }
        }
    }
    __syncthreads();
    if (!(w & 1)) {
        #pragma unroll
        for (int r = 0; r < 4; r++) {
            int rl = 4 * lg + r;
            float m1 = Mo[w | 1][rl], d1 = Do[w | 1][rl];
            float m = fmaxf(m_[r], m1);
            float a0 = __expf(m_[r] - m), a1 = __expf(m1 - m);
            float dd = d_[r] * a0 + d1 * a1;
            float inv = dd > 0.f ? 1.f / dd : 0.f;
            int row = rbase + rl;
            #pragma unroll
            for (int dt = 0; dt < 4; dt++) {
                float v = (o[dt][r] * a0 + Oo[w >> 1][rl][dt * 16 + lr] * a1) * inv;
                xw[(((b << 10) + row) << 9) + (h << 6) + dt * 16 + lr] = (bf16)v;
            }
        }
    }
}

extern "C" void kernel_launch(void* const* d_in, const int* in_sizes, int n_in,
                              void* d_out, int out_size, void* d_ws, size_t ws_size,
                              hipStream_t stream) {
    const float* query  = (const float*)d_in[0];
    const float* key_in = (const float*)d_in[1];
    const float* value  = (const float*)d_in[2];
    const int*   mask   = (const int*)d_in[3];
    const float* Wq     = (const float*)d_in[4];
    const float* bq     = (const float*)d_in[5];
    const float* Wv     = (const float*)d_in[6];
    const float* bv     = (const float*)d_in[7];
    const float* Wo     = (const float*)d_in[8];
    const float* bo     = (const float*)d_in[9];
    const float* v_bias = (const float*)d_in[10];

    char* ws = (char*)d_ws;
    bf16*  pe_b = (bf16*)(ws);                           // 256 KB (swizzled)
    float* vb   = (float*)(ws + 262144);                 // 64 KB
    bf16*  q_ws = (bf16*)(ws + 327680);                  // 8 MB  [bh][t][dh]
    bf16*  v_ws = (bf16*)(ws + 327680 + 8388608);        // 8 MB  V^T fragment-swizzled
    bf16*  x_ws = (bf16*)(ws + 327680 + 16777216);       // 8 MB  [b*t][512]
    bf16*  wt_q = (bf16*)(ws + 327680 + 25165824);       // 512 KB  Wq^T bf16
    bf16*  wt_v = (bf16*)(ws + 327680 + 25690112);       // 512 KB  Wv^T bf16
    bf16*  wt_o = (bf16*)(ws + 327680 + 26214400);       // 512 KB  Wo^T bf16
    // k_ws lives in d_out's first 8 MB; consumed before proj_o writes d_out.
    bf16*  k_ws = (bf16*)d_out;

    tables_kernel<<<768, 256, 0, stream>>>(v_bias, Wq, Wv, Wo, pe_b, vb, wt_q, wt_v, wt_o);
    kcvt_kernel<<<4096, 256, 0, stream>>>(key_in, k_ws);
    proj_qv<<<dim3(128, 8, 2), 256, 0, stream>>>(query, value, wt_q, wt_v, bq, bv, q_ws, v_ws);
    tener_attn<<<dim3(64, 32), 256, 0, stream>>>(q_ws, k_ws, v_ws, mask, pe_b, vb, x_ws);
    proj_o<<<dim3(128, 8), 256, 0, stream>>>(x_ws, wt_o, bo, (float*)d_out);
}

// Round 14
// 121.988 us; speedup vs baseline: 1.2855x; 1.0907x over previous
//
#include <hip/hip_runtime.h>
#include <hip/hip_bf16.h>

// B=8, T=1024, D=512, H=8, DH=64, VS=512
typedef __bf16 bf16;
typedef __bf16 bf16x8 __attribute__((ext_vector_type(8)));
typedef __bf16 bf16x4 __attribute__((ext_vector_type(4)));
typedef float f32x4 __attribute__((ext_vector_type(4)));

#define NEGBIG (-3.0e38f)

__device__ inline f32x4 mfma16(bf16x8 a, bf16x8 b, f32x4 c) {
    return __builtin_amdgcn_mfma_f32_16x16x32_bf16(a, b, c, 0, 0, 0);
}
__device__ inline bf16x8 ld8(const bf16* p) { return *reinterpret_cast<const bf16x8*>(p); }
__device__ inline f32x4 ldf4(const float* p) { return *reinterpret_cast<const f32x4*>(p); }

// DPP row (16-lane) rotate: pure-VALU cross-lane, no LDS round-trip
template<int CTRL>
__device__ inline float rowror(float x) {
    int xi = __builtin_bit_cast(int, x);
    int yi = __builtin_amdgcn_update_dpp(xi, xi, CTRL, 0xF, 0xF, false);
    return __builtin_bit_cast(float, yi);
}
__device__ inline float rowmax16(float x) {
    x = fmaxf(x, rowror<0x121>(x));
    x = fmaxf(x, rowror<0x122>(x));
    x = fmaxf(x, rowror<0x124>(x));
    x = fmaxf(x, rowror<0x128>(x));
    return x;
}
__device__ inline float rowsum16(float x) {
    x += rowror<0x121>(x);
    x += rowror<0x122>(x);
    x += rowror<0x124>(x);
    x += rowror<0x128>(x);
    return x;
}

// ---------------- fused tables: pe2 (swizzled, pos=j in [0,1024)) + wcvt x3 ----------------
// blocks [0,256): pe2; [256,448): wcvt
__global__ __launch_bounds__(256) void tables_kernel(const float* __restrict__ W0, const float* __restrict__ W1,
                                                     const float* __restrict__ W2, bf16* __restrict__ pe2,
                                                     bf16* __restrict__ T0, bf16* __restrict__ T1,
                                                     bf16* __restrict__ T2) {
    __shared__ float tile[64][65];
    int bid = blockIdx.x;
    if (bid < 256) {
        int g = bid * 256 + threadIdx.x;       // 65536 = 1024 j x 64 d
        int j = g >> 6, d = g & 63;
        float w = __expf(-(float)(d & 31) * 0.29710775393471563f);   // ln(10000)/31
        float ang = (float)j * w;
        float v = (d < 32) ? sinf(ang) : cosf(ang);
        int idx = (((j >> 4) << 1) + (d >> 5)) * 512 + (((d >> 3) & 3) * 16 + (j & 15)) * 8 + (d & 7);
        pe2[idx] = (bf16)v;
    } else {
        int wb = bid - 256;
        int which = wb >> 6, bidx = wb & 63;
        const float* W = which == 0 ? W0 : which == 1 ? W1 : W2;
        bf16* Wt = which == 0 ? T0 : which == 1 ? T1 : T2;
        int tx = bidx & 7, ty = bidx >> 3;
        int lane = threadIdx.x & 63, w = threadIdx.x >> 6;
        #pragma unroll
        for (int i = 0; i < 16; i++) {
            int k = ty * 64 + w * 16 + i;
            tile[w * 16 + i][lane] = W[k * 512 + tx * 64 + lane];
        }
        __syncthreads();
        #pragma unroll
        for (int i = 0; i < 16; i++) {
            int n = tx * 64 + w * 16 + i;
            Wt[n * 512 + ty * 64 + lane] = (bf16)tile[lane][w * 16 + i];
        }
    }
}

// ---------------- key convert: fp32 [b][t][h*64+dh] -> fragment-swizzled bf16 ----------------
__global__ void kcvt_kernel(const float* __restrict__ kin, bf16* __restrict__ kw) {
    int i = (blockIdx.x * 256 + threadIdx.x) * 4;
    f32x4 v = ldf4(kin + i);
    int dh = i & 63, hh = (i >> 6) & 7, t = (i >> 9) & 1023, b = i >> 19;
    int bh = (b << 3) + hh;
    bf16x4 o;
    #pragma unroll
    for (int e = 0; e < 4; e++) o[e] = (bf16)v[e];
    int blk = ((bh << 6) + (t >> 4)) * 2 + (dh >> 5);
    int off = (((dh >> 3) & 3) * 16 + (t & 15)) * 8 + (dh & 7);
    *reinterpret_cast<bf16x4*>(kw + blk * 512 + off) = o;
}

// ---------------- q-augment: q2[row] = R(-t)(q[row] + v_bias[h])  (RoPE identity) ----------------
// rel[i][j]+vb[h][j-i] == q2_i . pe2[j]  -- folds the whole TENER rel band into a GEMM.
__global__ void qaug_kernel(const bf16* __restrict__ qw, const float* __restrict__ v_bias,
                            bf16* __restrict__ q2) {
    int g = blockIdx.x * 256 + threadIdx.x;   // 2,097,152 = 65536 rows x 32 pairs
    int row = g >> 5, dp = g & 31;            // row = bh*1024 + t
    int t = row & 1023, h = (row >> 10) & 7;
    float qs = (float)qw[row * 64 + dp];
    float qc = (float)qw[row * 64 + 32 + dp];
    float as = qs + v_bias[h * 64 + dp];
    float ac = qc + v_bias[h * 64 + 32 + dp];
    float w = __expf(-(float)dp * 0.29710775393471563f);
    float sa, ca;
    __sincosf((float)t * w, &sa, &ca);
    q2[row * 64 + dp]      = (bf16)(as * ca + ac * sa);
    q2[row * 64 + 32 + dp] = (bf16)(ac * ca - as * sa);
}

// ---------------- merged q+v proj: 64x64/BK32, pre-transposed bf16 W ----------------
// blockIdx.z==0: query -> q_ws (linear [bh][t][dh]); z==1: value -> v_ws (fragment-swizzled V^T)
__global__ __launch_bounds__(256) void proj_qv(const float* __restrict__ Q, const float* __restrict__ V,
                                               const bf16* __restrict__ WtQ, const bf16* __restrict__ WtV,
                                               const float* __restrict__ bq, const float* __restrict__ bv,
                                               bf16* __restrict__ q_ws, bf16* __restrict__ v_ws) {
    __shared__ bf16 As[64][40];
    __shared__ bf16 Bs[64][40];
    int isv = blockIdx.z;
    const float* A = isv ? V : Q;
    const bf16* Wt = isv ? WtV : WtQ;
    const float* bias = isv ? bv : bq;
    int row0 = blockIdx.x * 64, n0 = blockIdx.y * 64;
    int tid = threadIdx.x, lane = tid & 63, w = tid >> 6, lg = lane >> 4, lr = lane & 15;
    int wm = (w >> 1) * 32, wn = (w & 1) * 32;
    f32x4 acc[2][2] = {};
    for (int k0 = 0; k0 < 512; k0 += 32) {
        int r = tid >> 2, kq = (tid & 3) * 8;
        f32x4 a0 = ldf4(A + (row0 + r) * 512 + k0 + kq);
        f32x4 a1 = ldf4(A + (row0 + r) * 512 + k0 + kq + 4);
        bf16x8 av;
        #pragma unroll
        for (int e = 0; e < 4; e++) { av[e] = (bf16)a0[e]; av[4 + e] = (bf16)a1[e]; }
        bf16x8 bv8 = ld8(Wt + (n0 + r) * 512 + k0 + kq);
        __syncthreads();
        *reinterpret_cast<bf16x8*>(&As[r][kq]) = av;
        *reinterpret_cast<bf16x8*>(&Bs[r][kq]) = bv8;
        __syncthreads();
        bf16x8 aa0 = ld8(&As[wm + lr][lg * 8]);
        bf16x8 aa1 = ld8(&As[wm + 16 + lr][lg * 8]);
        bf16x8 bb0 = ld8(&Bs[wn + lr][lg * 8]);
        bf16x8 bb1 = ld8(&Bs[wn + 16 + lr][lg * 8]);
        acc[0][0] = mfma16(aa0, bb0, acc[0][0]);
        acc[0][1] = mfma16(aa0, bb1, acc[0][1]);
        acc[1][0] = mfma16(aa1, bb0, acc[1][0]);
        acc[1][1] = mfma16(aa1, bb1, acc[1][1]);
    }
    #pragma unroll
    for (int mi = 0; mi < 2; mi++)
    #pragma unroll
    for (int ni = 0; ni < 2; ni++) {
        int rowb = row0 + wm + mi * 16 + lg * 4;
        int col = n0 + wn + ni * 16 + lr;
        int b = rowb >> 10, t = rowb & 1023, hh = col >> 6, dh = col & 63;
        int bh = (b << 3) + hh;
        if (isv) {
            int blk = (((bh << 4) + (t >> 6)) * 2 + ((t >> 5) & 1)) * 4 + (dh >> 4);
            int off = (((t >> 3) & 3) * 16 + (dh & 15)) * 8 + (t & 7);
            bf16x4 o4;
            #pragma unroll
            for (int rr = 0; rr < 4; rr++) o4[rr] = (bf16)((float)acc[mi][ni][rr] + bias[col]);
            *reinterpret_cast<bf16x4*>(v_ws + blk * 512 + off) = o4;
        } else {
            #pragma unroll
            for (int rr = 0; rr < 4; rr++) {
                float v = (float)acc[mi][ni][rr] + bias[col];
                q_ws[((bh << 10) + t + rr) * 64 + dh] = (bf16)v;
            }
        }
    }
}

// ---------------- output proj: 64x64/BK32, bf16 A (x_ws), fp32 out ----------------
__global__ __launch_bounds__(256) void proj_o(const bf16* __restrict__ Ap, const bf16* __restrict__ Wt,
                                              const float* __restrict__ bias, float* __restrict__ outp) {
    __shared__ bf16 As[64][40];
    __shared__ bf16 Bs[64][40];
    int row0 = blockIdx.x * 64, n0 = blockIdx.y * 64;
    int tid = threadIdx.x, lane = tid & 63, w = tid >> 6, lg = lane >> 4, lr = lane & 15;
    int wm = (w >> 1) * 32, wn = (w & 1) * 32;
    f32x4 acc[2][2] = {};
    for (int k0 = 0; k0 < 512; k0 += 32) {
        int r = tid >> 2, kq = (tid & 3) * 8;
        bf16x8 av = ld8(Ap + (row0 + r) * 512 + k0 + kq);
        bf16x8 bv = ld8(Wt + (n0 + r) * 512 + k0 + kq);
        __syncthreads();
        *reinterpret_cast<bf16x8*>(&As[r][kq]) = av;
        *reinterpret_cast<bf16x8*>(&Bs[r][kq]) = bv;
        __syncthreads();
        bf16x8 a0 = ld8(&As[wm + lr][lg * 8]);
        bf16x8 a1 = ld8(&As[wm + 16 + lr][lg * 8]);
        bf16x8 b0 = ld8(&Bs[wn + lr][lg * 8]);
        bf16x8 b1 = ld8(&Bs[wn + 16 + lr][lg * 8]);
        acc[0][0] = mfma16(a0, b0, acc[0][0]);
        acc[0][1] = mfma16(a0, b1, acc[0][1]);
        acc[1][0] = mfma16(a1, b0, acc[1][0]);
        acc[1][1] = mfma16(a1, b1, acc[1][1]);
    }
    #pragma unroll
    for (int mi = 0; mi < 2; mi++)
    #pragma unroll
    for (int ni = 0; ni < 2; ni++) {
        int rowb = row0 + wm + mi * 16 + lg * 4;
        int col = n0 + wn + ni * 16 + lr;
        #pragma unroll
        for (int rr = 0; rr < 4; rr++)
            outp[(rowb + rr) * 512 + col] = (float)acc[mi][ni][rr] + bias[col];
    }
}

// ---------------- fused TENER attention: rel folded into augmented QK GEMM ----------------
// grid (64 bh, 32 qt-pairs), block 256 = 4 waves:
//   wave w -> q-tile (blockIdx.y*2 + (w>>1)), j-half (w&1). Pair merges at end.
// Logit S[i][j] = q_i.k_j + q2_i.pe2[j]  (q2 = rotated q+vb, qaug_kernel).
// (256,4) measured-best; tighter bounds or extra live state spills (r5/r10/r12).
__global__ __launch_bounds__(256, 4) void tener_attn(const bf16* __restrict__ qw, const bf16* __restrict__ q2,
                                                     const bf16* __restrict__ kw, const bf16* __restrict__ vt,
                                                     const int* __restrict__ mask, const bf16* __restrict__ pe2,
                                                     bf16* __restrict__ xw) {
    __shared__ bf16 Pl[4][16][76];     // per-wave P relayout
    __shared__ float Mo[4][16], Do[4][16];
    __shared__ float Oo[2][16][65];    // odd-wave partial O per pair
    int bh = blockIdx.x, b = bh >> 3, h = bh & 7;
    (void)h;
    int tid = threadIdx.x, w = tid >> 6, lane = tid & 63, lg = lane >> 4, lr = lane & 15;
    int rbase = (blockIdx.y * 2 + (w >> 1)) * 16;
    int jh = w & 1;

    const int* mkb = mask + (b << 10);

    int qoff = ((bh << 10) + rbase + lr) * 64 + lg * 8;
    bf16x8 aq0 = ld8(qw + qoff);
    bf16x8 aq1 = ld8(qw + qoff + 32);
    bf16x8 aq2 = ld8(q2 + qoff);
    bf16x8 aq3 = ld8(q2 + qoff + 32);

    f32x4 o[4] = {};
    float m_[4], d_[4];
    #pragma unroll
    for (int r = 0; r < 4; r++) { m_[r] = NEGBIG; d_[r] = 0.f; }

    for (int tt = 0; tt < 8; tt++) {
        __builtin_amdgcn_sched_barrier(0x7F);   // DS may not cross

        int j0 = jh * 512 + tt * 64;

        // S = [q;q2] . [k;pe2]^T — all fragment loads fully coalesced
        f32x4 s[4];
        int kblk = (bh << 6) + (j0 >> 4);
        int pblk = j0 >> 4;
        #pragma unroll
        for (int nt = 0; nt < 4; nt++) {
            const bf16* kp = kw + (((kblk + nt) << 1)) * 512 + lane * 8;
            const bf16* pp = pe2 + (((pblk + nt) << 1)) * 512 + lane * 8;
            f32x4 acc = {};
            acc = mfma16(aq0, ld8(kp), acc);
            acc = mfma16(aq1, ld8(kp + 512), acc);
            acc = mfma16(aq2, ld8(pp), acc);
            acc = mfma16(aq3, ld8(pp + 512), acc);
            s[nt] = acc;
        }

        int mk[4];
        #pragma unroll
        for (int nt = 0; nt < 4; nt++) mk[nt] = mkb[j0 + nt * 16 + lr];

        // online softmax — no gathers needed; s already holds full logits
        #pragma unroll
        for (int r = 0; r < 4; r++) {
            int rl = 4 * lg + r;
            float sv[4];
            #pragma unroll
            for (int nt = 0; nt < 4; nt++) sv[nt] = mk[nt] ? (float)s[nt][r] : NEGBIG;
            float mx = fmaxf(fmaxf(sv[0], sv[1]), fmaxf(sv[2], sv[3]));
            mx = rowmax16(mx);
            float nm = fmaxf(m_[r], mx);
            float sc = __expf(m_[r] - nm);
            float p[4], rs = 0.f;
            #pragma unroll
            for (int nt = 0; nt < 4; nt++) {
                p[nt] = mk[nt] ? __expf(sv[nt] - nm) : 0.f;
                rs += p[nt];
            }
            rs = rowsum16(rs);
            d_[r] = d_[r] * sc + rs;
            m_[r] = nm;
            #pragma unroll
            for (int dt = 0; dt < 4; dt++) o[dt][r] *= sc;
            #pragma unroll
            for (int nt = 0; nt < 4; nt++) Pl[w][rl][nt * 16 + lr] = (bf16)p[nt];
        }

        __builtin_amdgcn_sched_barrier(0x7F);   // DS may not cross (Pl WAR/RAW fence)

        // O += P.V — V^T fragment loads fully coalesced
        int vblk0 = ((((bh << 4) + (j0 >> 6)) << 1)) << 2;
        #pragma unroll
        for (int ks = 0; ks < 2; ks++) {
            bf16x8 ap = ld8(&Pl[w][lr][ks * 32 + lg * 8]);
            #pragma unroll
            for (int dt = 0; dt < 4; dt++) {
                const bf16* vp = vt + (vblk0 + (ks << 2) + dt) * 512 + lane * 8;
                o[dt] = mfma16(ap, ld8(vp), o[dt]);
            }
        }
    }

    // pair-merge: odd wave publishes partials, even wave combines + writes
    if (w & 1) {
        #pragma unroll
        for (int dt = 0; dt < 4; dt++)
        #pragma unroll
        for (int r = 0; r < 4; r++)
            Oo[w >> 1][4 * lg + r][dt * 16 + lr] = o[dt][r];
        if (lr == 0) {
            #pragma unroll
            for (int r = 0; r < 4; r++) { Mo[w][4 * lg + r] = m_[r]; Do[w][4 * lg + r] = d_[r]; }
        }
    }
    __syncthreads();
    if (!(w & 1)) {
        #pragma unroll
        for (int r = 0; r < 4; r++) {
            int rl = 4 * lg + r;
            float m1 = Mo[w | 1][rl], d1 = Do[w | 1][rl];
            float m = fmaxf(m_[r], m1);
            float a0 = __expf(m_[r] - m), a1 = __expf(m1 - m);
            float dd = d_[r] * a0 + d1 * a1;
            float inv = dd > 0.f ? 1.f / dd : 0.f;
            int row = rbase + rl;
            #pragma unroll
            for (int dt = 0; dt < 4; dt++) {
                float v = (o[dt][r] * a0 + Oo[w >> 1][rl][dt * 16 + lr] * a1) * inv;
                xw[(((b << 10) + row) << 9) + ((bh & 7) << 6) + dt * 16 + lr] = (bf16)v;
            }
        }
    }
}

extern "C" void kernel_launch(void* const* d_in, const int* in_sizes, int n_in,
                              void* d_out, int out_size, void* d_ws, size_t ws_size,
                              hipStream_t stream) {
    const float* query  = (const float*)d_in[0];
    const float* key_in = (const float*)d_in[1];
    const float* value  = (const float*)d_in[2];
    const int*   mask   = (const int*)d_in[3];
    const float* Wq     = (const float*)d_in[4];
    const float* bq     = (const float*)d_in[5];
    const float* Wv     = (const float*)d_in[6];
    const float* bv     = (const float*)d_in[7];
    const float* Wo     = (const float*)d_in[8];
    const float* bo     = (const float*)d_in[9];
    const float* v_bias = (const float*)d_in[10];

    char* ws = (char*)d_ws;
    bf16*  pe2  = (bf16*)(ws);                           // 128 KB (swizzled, pos=j)
    bf16*  q_ws = (bf16*)(ws + 327680);                  // 8 MB  [bh][t][dh]
    bf16*  v_ws = (bf16*)(ws + 327680 + 8388608);        // 8 MB  V^T fragment-swizzled
    bf16*  x_ws = (bf16*)(ws + 327680 + 16777216);       // 8 MB  [b*t][512]
    bf16*  wt_q = (bf16*)(ws + 327680 + 25165824);       // 512 KB  Wq^T bf16
    bf16*  wt_v = (bf16*)(ws + 327680 + 25690112);       // 512 KB  Wv^T bf16
    bf16*  wt_o = (bf16*)(ws + 327680 + 26214400);       // 512 KB  Wo^T bf16
    // d_out (16 MB) hosts k_ws (first 8 MB) and q2_ws (second 8 MB); both fully
    // consumed by tener_attn before proj_o overwrites d_out.
    bf16*  k_ws = (bf16*)d_out;
    bf16*  q2_ws = (bf16*)((char*)d_out + 8388608);

    tables_kernel<<<448, 256, 0, stream>>>(Wq, Wv, Wo, pe2, wt_q, wt_v, wt_o);
    kcvt_kernel<<<4096, 256, 0, stream>>>(key_in, k_ws);
    proj_qv<<<dim3(128, 8, 2), 256, 0, stream>>>(query, value, wt_q, wt_v, bq, bv, q_ws, v_ws);
    qaug_kernel<<<8192, 256, 0, stream>>>(q_ws, v_bias, q2_ws);
    tener_attn<<<dim3(64, 32), 256, 0, stream>>>(q_ws, q2_ws, k_ws, v_ws, mask, pe2, x_ws);
    proj_o<<<dim3(128, 8), 256, 0, stream>>>(x_ws, wt_o, bo, (float*)d_out);
}

// Round 15
// 118.593 us; speedup vs baseline: 1.3223x; 1.0286x over previous
//
#include <hip/hip_runtime.h>
#include <hip/hip_bf16.h>

// B=8, T=1024, D=512, H=8, DH=64, VS=512
typedef __bf16 bf16;
typedef __bf16 bf16x8 __attribute__((ext_vector_type(8)));
typedef __bf16 bf16x4 __attribute__((ext_vector_type(4)));
typedef float f32x4 __attribute__((ext_vector_type(4)));

#define NEGBIG (-3.0e38f)

__device__ inline f32x4 mfma16(bf16x8 a, bf16x8 b, f32x4 c) {
    return __builtin_amdgcn_mfma_f32_16x16x32_bf16(a, b, c, 0, 0, 0);
}
__device__ inline bf16x8 ld8(const bf16* p) { return *reinterpret_cast<const bf16x8*>(p); }
__device__ inline f32x4 ldf4(const float* p) { return *reinterpret_cast<const f32x4*>(p); }

// DPP row (16-lane) rotate: pure-VALU cross-lane, no LDS round-trip
template<int CTRL>
__device__ inline float rowror(float x) {
    int xi = __builtin_bit_cast(int, x);
    int yi = __builtin_amdgcn_update_dpp(xi, xi, CTRL, 0xF, 0xF, false);
    return __builtin_bit_cast(float, yi);
}
__device__ inline float rowmax16(float x) {
    x = fmaxf(x, rowror<0x121>(x));
    x = fmaxf(x, rowror<0x122>(x));
    x = fmaxf(x, rowror<0x124>(x));
    x = fmaxf(x, rowror<0x128>(x));
    return x;
}
__device__ inline float rowsum16(float x) {
    x += rowror<0x121>(x);
    x += rowror<0x122>(x);
    x += rowror<0x124>(x);
    x += rowror<0x128>(x);
    return x;
}

// ---------------- fused tables: pe2 (swizzled) + wcvt x3 + kcvt ----------------
// blocks [0,256): pe2; [256,448): wcvt; [448,4544): kcvt
__global__ __launch_bounds__(256) void tables_kernel(const float* __restrict__ W0, const float* __restrict__ W1,
                                                     const float* __restrict__ W2, const float* __restrict__ kin,
                                                     bf16* __restrict__ pe2, bf16* __restrict__ T0,
                                                     bf16* __restrict__ T1, bf16* __restrict__ T2,
                                                     bf16* __restrict__ kw) {
    __shared__ float tile[64][65];
    int bid = blockIdx.x;
    if (bid < 256) {
        int g = bid * 256 + threadIdx.x;       // 65536 = 1024 j x 64 d
        int j = g >> 6, d = g & 63;
        float w = __expf(-(float)(d & 31) * 0.29710775393471563f);   // ln(10000)/31
        float ang = (float)j * w;
        float v = (d < 32) ? sinf(ang) : cosf(ang);
        int idx = (((j >> 4) << 1) + (d >> 5)) * 512 + (((d >> 3) & 3) * 16 + (j & 15)) * 8 + (d & 7);
        pe2[idx] = (bf16)v;
    } else if (bid < 448) {
        int wb = bid - 256;
        int which = wb >> 6, bidx = wb & 63;
        const float* W = which == 0 ? W0 : which == 1 ? W1 : W2;
        bf16* Wt = which == 0 ? T0 : which == 1 ? T1 : T2;
        int tx = bidx & 7, ty = bidx >> 3;
        int lane = threadIdx.x & 63, w = threadIdx.x >> 6;
        #pragma unroll
        for (int i = 0; i < 16; i++) {
            int k = ty * 64 + w * 16 + i;
            tile[w * 16 + i][lane] = W[k * 512 + tx * 64 + lane];
        }
        __syncthreads();
        #pragma unroll
        for (int i = 0; i < 16; i++) {
            int n = tx * 64 + w * 16 + i;
            Wt[n * 512 + ty * 64 + lane] = (bf16)tile[lane][w * 16 + i];
        }
    } else {
        int i = ((bid - 448) * 256 + threadIdx.x) * 4;
        f32x4 v = ldf4(kin + i);
        int dh = i & 63, hh = (i >> 6) & 7, t = (i >> 9) & 1023, b = i >> 19;
        int bh = (b << 3) + hh;
        bf16x4 o;
        #pragma unroll
        for (int e = 0; e < 4; e++) o[e] = (bf16)v[e];
        int blk = ((bh << 6) + (t >> 4)) * 2 + (dh >> 5);
        int off = (((dh >> 3) & 3) * 16 + (t & 15)) * 8 + (dh & 7);
        *reinterpret_cast<bf16x4*>(kw + blk * 512 + off) = o;
    }
}

// ---------------- merged q+v proj: 64x64/BK32, pre-transposed bf16 W ----------------
// blockIdx.z==0: query -> q_ws (linear [bh][t][dh]); z==1: value -> v_ws (fragment-swizzled V^T)
__global__ __launch_bounds__(256) void proj_qv(const float* __restrict__ Q, const float* __restrict__ V,
                                               const bf16* __restrict__ WtQ, const bf16* __restrict__ WtV,
                                               const float* __restrict__ bq, const float* __restrict__ bv,
                                               bf16* __restrict__ q_ws, bf16* __restrict__ v_ws) {
    __shared__ bf16 As[64][40];
    __shared__ bf16 Bs[64][40];
    int isv = blockIdx.z;
    const float* A = isv ? V : Q;
    const bf16* Wt = isv ? WtV : WtQ;
    const float* bias = isv ? bv : bq;
    int row0 = blockIdx.x * 64, n0 = blockIdx.y * 64;
    int tid = threadIdx.x, lane = tid & 63, w = tid >> 6, lg = lane >> 4, lr = lane & 15;
    int wm = (w >> 1) * 32, wn = (w & 1) * 32;
    f32x4 acc[2][2] = {};
    for (int k0 = 0; k0 < 512; k0 += 32) {
        int r = tid >> 2, kq = (tid & 3) * 8;
        f32x4 a0 = ldf4(A + (row0 + r) * 512 + k0 + kq);
        f32x4 a1 = ldf4(A + (row0 + r) * 512 + k0 + kq + 4);
        bf16x8 av;
        #pragma unroll
        for (int e = 0; e < 4; e++) { av[e] = (bf16)a0[e]; av[4 + e] = (bf16)a1[e]; }
        bf16x8 bv8 = ld8(Wt + (n0 + r) * 512 + k0 + kq);
        __syncthreads();
        *reinterpret_cast<bf16x8*>(&As[r][kq]) = av;
        *reinterpret_cast<bf16x8*>(&Bs[r][kq]) = bv8;
        __syncthreads();
        bf16x8 aa0 = ld8(&As[wm + lr][lg * 8]);
        bf16x8 aa1 = ld8(&As[wm + 16 + lr][lg * 8]);
        bf16x8 bb0 = ld8(&Bs[wn + lr][lg * 8]);
        bf16x8 bb1 = ld8(&Bs[wn + 16 + lr][lg * 8]);
        acc[0][0] = mfma16(aa0, bb0, acc[0][0]);
        acc[0][1] = mfma16(aa0, bb1, acc[0][1]);
        acc[1][0] = mfma16(aa1, bb0, acc[1][0]);
        acc[1][1] = mfma16(aa1, bb1, acc[1][1]);
    }
    #pragma unroll
    for (int mi = 0; mi < 2; mi++)
    #pragma unroll
    for (int ni = 0; ni < 2; ni++) {
        int rowb = row0 + wm + mi * 16 + lg * 4;
        int col = n0 + wn + ni * 16 + lr;
        int b = rowb >> 10, t = rowb & 1023, hh = col >> 6, dh = col & 63;
        int bh = (b << 3) + hh;
        if (isv) {
            int blk = (((bh << 4) + (t >> 6)) * 2 + ((t >> 5) & 1)) * 4 + (dh >> 4);
            int off = (((t >> 3) & 3) * 16 + (dh & 15)) * 8 + (t & 7);
            bf16x4 o4;
            #pragma unroll
            for (int rr = 0; rr < 4; rr++) o4[rr] = (bf16)((float)acc[mi][ni][rr] + bias[col]);
            *reinterpret_cast<bf16x4*>(v_ws + blk * 512 + off) = o4;
        } else {
            #pragma unroll
            for (int rr = 0; rr < 4; rr++) {
                float v = (float)acc[mi][ni][rr] + bias[col];
                q_ws[((bh << 10) + t + rr) * 64 + dh] = (bf16)v;
            }
        }
    }
}

// ---------------- output proj: 64x64/BK32, bf16 A (x_ws), fp32 out ----------------
__global__ __launch_bounds__(256) void proj_o(const bf16* __restrict__ Ap, const bf16* __restrict__ Wt,
                                              const float* __restrict__ bias, float* __restrict__ outp) {
    __shared__ bf16 As[64][40];
    __shared__ bf16 Bs[64][40];
    int row0 = blockIdx.x * 64, n0 = blockIdx.y * 64;
    int tid = threadIdx.x, lane = tid & 63, w = tid >> 6, lg = lane >> 4, lr = lane & 15;
    int wm = (w >> 1) * 32, wn = (w & 1) * 32;
    f32x4 acc[2][2] = {};
    for (int k0 = 0; k0 < 512; k0 += 32) {
        int r = tid >> 2, kq = (tid & 3) * 8;
        bf16x8 av = ld8(Ap + (row0 + r) * 512 + k0 + kq);
        bf16x8 bv = ld8(Wt + (n0 + r) * 512 + k0 + kq);
        __syncthreads();
        *reinterpret_cast<bf16x8*>(&As[r][kq]) = av;
        *reinterpret_cast<bf16x8*>(&Bs[r][kq]) = bv;
        __syncthreads();
        bf16x8 a0 = ld8(&As[wm + lr][lg * 8]);
        bf16x8 a1 = ld8(&As[wm + 16 + lr][lg * 8]);
        bf16x8 b0 = ld8(&Bs[wn + lr][lg * 8]);
        bf16x8 b1 = ld8(&Bs[wn + 16 + lr][lg * 8]);
        acc[0][0] = mfma16(a0, b0, acc[0][0]);
        acc[0][1] = mfma16(a0, b1, acc[0][1]);
        acc[1][0] = mfma16(a1, b0, acc[1][0]);
        acc[1][1] = mfma16(a1, b1, acc[1][1]);
    }
    #pragma unroll
    for (int mi = 0; mi < 2; mi++)
    #pragma unroll
    for (int ni = 0; ni < 2; ni++) {
        int rowb = row0 + wm + mi * 16 + lg * 4;
        int col = n0 + wn + ni * 16 + lr;
        #pragma unroll
        for (int rr = 0; rr < 4; rr++)
            outp[(rowb + rr) * 512 + col] = (float)acc[mi][ni][rr] + bias[col];
    }
}

// ---------------- fused TENER attention: rel folded into augmented QK GEMM ----------------
// grid (64 bh, 32 qt-pairs), block 256 = 4 waves. Logit S[i][j] = q_i.k_j + q2_i.pe2[j],
// q2 built IN-REGISTER in the prologue (RoPE fold of rel+vb; bit-identical to qaug kernel).
// (256,4) measured-best; tighter bounds or extra live state spills (r5/r10/r12).
__global__ __launch_bounds__(256, 4) void tener_attn(const bf16* __restrict__ qw, const bf16* __restrict__ kw,
                                                     const bf16* __restrict__ vt, const int* __restrict__ mask,
                                                     const bf16* __restrict__ pe2, const float* __restrict__ v_bias,
                                                     bf16* __restrict__ xw) {
    __shared__ bf16 Pl[4][16][76];     // per-wave P relayout
    __shared__ float Mo[4][16], Do[4][16];
    __shared__ float Oo[2][16][65];    // odd-wave partial O per pair
    int bh = blockIdx.x, b = bh >> 3, h = bh & 7;
    int tid = threadIdx.x, w = tid >> 6, lane = tid & 63, lg = lane >> 4, lr = lane & 15;
    int rbase = (blockIdx.y * 2 + (w >> 1)) * 16;
    int jh = w & 1;

    const int* mkb = mask + (b << 10);

    int qoff = ((bh << 10) + rbase + lr) * 64 + lg * 8;
    bf16x8 aq0 = ld8(qw + qoff);
    bf16x8 aq1 = ld8(qw + qoff + 32);

    // build q2 fragments in-register: q2 = R(-t)(q + v_bias[h]).
    // lane-local: aq0[e]/aq1[e] are the matched (sin,cos) element pair (d, d+32).
    bf16x8 aq2, aq3;
    {
        int t = rbase + lr;
        const float* vbp = v_bias + (h << 6) + lg * 8;
        #pragma unroll
        for (int e = 0; e < 8; e++) {
            int d = lg * 8 + e;
            float as = (float)aq0[e] + vbp[e];
            float ac = (float)aq1[e] + vbp[32 + e];
            float w_ = __expf(-(float)d * 0.29710775393471563f);
            float sa, ca;
            __sincosf((float)t * w_, &sa, &ca);
            aq2[e] = (bf16)(as * ca + ac * sa);
            aq3[e] = (bf16)(ac * ca - as * sa);
        }
    }

    f32x4 o[4] = {};
    float m_[4], d_[4];
    #pragma unroll
    for (int r = 0; r < 4; r++) { m_[r] = NEGBIG; d_[r] = 0.f; }

    for (int tt = 0; tt < 8; tt++) {
        __builtin_amdgcn_sched_barrier(0x7F);   // DS may not cross

        int j0 = jh * 512 + tt * 64;

        // S = [q;q2] . [k;pe2]^T — all fragment loads fully coalesced
        f32x4 s[4];
        int kblk = (bh << 6) + (j0 >> 4);
        int pblk = j0 >> 4;
        #pragma unroll
        for (int nt = 0; nt < 4; nt++) {
            const bf16* kp = kw + (((kblk + nt) << 1)) * 512 + lane * 8;
            const bf16* pp = pe2 + (((pblk + nt) << 1)) * 512 + lane * 8;
            f32x4 acc = {};
            acc = mfma16(aq0, ld8(kp), acc);
            acc = mfma16(aq1, ld8(kp + 512), acc);
            acc = mfma16(aq2, ld8(pp), acc);
            acc = mfma16(aq3, ld8(pp + 512), acc);
            s[nt] = acc;
        }

        int mk[4];
        #pragma unroll
        for (int nt = 0; nt < 4; nt++) mk[nt] = mkb[j0 + nt * 16 + lr];

        // online softmax with exact defer-rescale: when no row-group raises its max,
        // sc == exp(0) == 1 -> skip rescale entirely (bit-identical).
        #pragma unroll
        for (int r = 0; r < 4; r++) {
            int rl = 4 * lg + r;
            float sv[4];
            #pragma unroll
            for (int nt = 0; nt < 4; nt++) sv[nt] = mk[nt] ? (float)s[nt][r] : NEGBIG;
            float mx = fmaxf(fmaxf(sv[0], sv[1]), fmaxf(sv[2], sv[3]));
            mx = rowmax16(mx);
            if (!__all(mx <= m_[r])) {
                float nm = fmaxf(m_[r], mx);
                float sc = __expf(m_[r] - nm);
                d_[r] *= sc;
                #pragma unroll
                for (int dt = 0; dt < 4; dt++) o[dt][r] *= sc;
                m_[r] = nm;
            }
            float p[4], rs = 0.f;
            #pragma unroll
            for (int nt = 0; nt < 4; nt++) {
                p[nt] = mk[nt] ? __expf(sv[nt] - m_[r]) : 0.f;
                rs += p[nt];
            }
            rs = rowsum16(rs);
            d_[r] += rs;
            #pragma unroll
            for (int nt = 0; nt < 4; nt++) Pl[w][rl][nt * 16 + lr] = (bf16)p[nt];
        }

        __builtin_amdgcn_sched_barrier(0x7F);   // DS may not cross (Pl WAR/RAW fence)

        // O += P.V — V^T fragment loads fully coalesced
        int vblk0 = ((((bh << 4) + (j0 >> 6)) << 1)) << 2;
        #pragma unroll
        for (int ks = 0; ks < 2; ks++) {
            bf16x8 ap = ld8(&Pl[w][lr][ks * 32 + lg * 8]);
            #pragma unroll
            for (int dt = 0; dt < 4; dt++) {
                const bf16* vp = vt + (vblk0 + (ks << 2) + dt) * 512 + lane * 8;
                o[dt] = mfma16(ap, ld8(vp), o[dt]);
            }
        }
    }

    // pair-merge: odd wave publishes partials, even wave combines + writes
    if (w & 1) {
        #pragma unroll
        for (int dt = 0; dt < 4; dt++)
        #pragma unroll
        for (int r = 0; r < 4; r++)
            Oo[w >> 1][4 * lg + r][dt * 16 + lr] = o[dt][r];
        if (lr == 0) {
            #pragma unroll
            for (int r = 0; r < 4; r++) { Mo[w][4 * lg + r] = m_[r]; Do[w][4 * lg + r] = d_[r]; }
        }
    }
    __syncthreads();
    if (!(w & 1)) {
        #pragma unroll
        for (int r = 0; r < 4; r++) {
            int rl = 4 * lg + r;
            float m1 = Mo[w | 1][rl], d1 = Do[w | 1][rl];
            float m = fmaxf(m_[r], m1);
            float a0 = __expf(m_[r] - m), a1 = __expf(m1 - m);
            float dd = d_[r] * a0 + d1 * a1;
            float inv = dd > 0.f ? 1.f / dd : 0.f;
            int row = rbase + rl;
            #pragma unroll
            for (int dt = 0; dt < 4; dt++) {
                float v = (o[dt][r] * a0 + Oo[w >> 1][rl][dt * 16 + lr] * a1) * inv;
                xw[(((b << 10) + row) << 9) + (h << 6) + dt * 16 + lr] = (bf16)v;
            }
        }
    }
}

extern "C" void kernel_launch(void* const* d_in, const int* in_sizes, int n_in,
                              void* d_out, int out_size, void* d_ws, size_t ws_size,
                              hipStream_t stream) {
    const float* query  = (const float*)d_in[0];
    const float* key_in = (const float*)d_in[1];
    const float* value  = (const float*)d_in[2];
    const int*   mask   = (const int*)d_in[3];
    const float* Wq     = (const float*)d_in[4];
    const float* bq     = (const float*)d_in[5];
    const float* Wv     = (const float*)d_in[6];
    const float* bv     = (const float*)d_in[7];
    const float* Wo     = (const float*)d_in[8];
    const float* bo     = (const float*)d_in[9];
    const float* v_bias = (const float*)d_in[10];

    char* ws = (char*)d_ws;
    bf16*  pe2  = (bf16*)(ws);                           // 128 KB (swizzled, pos=j)
    bf16*  q_ws = (bf16*)(ws + 327680);                  // 8 MB  [bh][t][dh]
    bf16*  v_ws = (bf16*)(ws + 327680 + 8388608);        // 8 MB  V^T fragment-swizzled
    bf16*  x_ws = (bf16*)(ws + 327680 + 16777216);       // 8 MB  [b*t][512]
    bf16*  wt_q = (bf16*)(ws + 327680 + 25165824);       // 512 KB  Wq^T bf16
    bf16*  wt_v = (bf16*)(ws + 327680 + 25690112);       // 512 KB  Wv^T bf16
    bf16*  wt_o = (bf16*)(ws + 327680 + 26214400);       // 512 KB  Wo^T bf16
    // k_ws lives in d_out's first 8 MB; fully consumed by tener_attn before
    // proj_o overwrites d_out.
    bf16*  k_ws = (bf16*)d_out;

    tables_kernel<<<4544, 256, 0, stream>>>(Wq, Wv, Wo, key_in, pe2, wt_q, wt_v, wt_o, k_ws);
    proj_qv<<<dim3(128, 8, 2), 256, 0, stream>>>(query, value, wt_q, wt_v, bq, bv, q_ws, v_ws);
    tener_attn<<<dim3(64, 32), 256, 0, stream>>>(q_ws, k_ws, v_ws, mask, pe2, v_bias, x_ws);
    proj_o<<<dim3(128, 8), 256, 0, stream>>>(x_ws, wt_o, bo, (float*)d_out);
}

// Round 16
// 111.971 us; speedup vs baseline: 1.4005x; 1.0591x over previous
//
#include <hip/hip_runtime.h>
#include <hip/hip_bf16.h>

// B=8, T=1024, D=512, H=8, DH=64, VS=512
typedef __bf16 bf16;
typedef __bf16 bf16x8 __attribute__((ext_vector_type(8)));
typedef __bf16 bf16x4 __attribute__((ext_vector_type(4)));
typedef float f32x4 __attribute__((ext_vector_type(4)));

#define NEGBIG (-3.0e38f)

__device__ inline f32x4 mfma16(bf16x8 a, bf16x8 b, f32x4 c) {
    return __builtin_amdgcn_mfma_f32_16x16x32_bf16(a, b, c, 0, 0, 0);
}
__device__ inline bf16x8 ld8(const bf16* p) { return *reinterpret_cast<const bf16x8*>(p); }
__device__ inline f32x4 ldf4(const float* p) { return *reinterpret_cast<const f32x4*>(p); }

// DPP row (16-lane) rotate: pure-VALU cross-lane, no LDS round-trip
template<int CTRL>
__device__ inline float rowror(float x) {
    int xi = __builtin_bit_cast(int, x);
    int yi = __builtin_amdgcn_update_dpp(xi, xi, CTRL, 0xF, 0xF, false);
    return __builtin_bit_cast(float, yi);
}
__device__ inline float rowmax16(float x) {
    x = fmaxf(x, rowror<0x121>(x));
    x = fmaxf(x, rowror<0x122>(x));
    x = fmaxf(x, rowror<0x124>(x));
    x = fmaxf(x, rowror<0x128>(x));
    return x;
}
__device__ inline float rowsum16(float x) {
    x += rowror<0x121>(x);
    x += rowror<0x122>(x);
    x += rowror<0x124>(x);
    x += rowror<0x128>(x);
    return x;
}

// ---------------- fused tables: pe2 (swizzled) + wcvt x3 + kcvt ----------------
// blocks [0,256): pe2; [256,448): wcvt; [448,4544): kcvt
__global__ __launch_bounds__(256) void tables_kernel(const float* __restrict__ W0, const float* __restrict__ W1,
                                                     const float* __restrict__ W2, const float* __restrict__ kin,
                                                     bf16* __restrict__ pe2, bf16* __restrict__ T0,
                                                     bf16* __restrict__ T1, bf16* __restrict__ T2,
                                                     bf16* __restrict__ kw) {
    __shared__ float tile[64][65];
    int bid = blockIdx.x;
    if (bid < 256) {
        int g = bid * 256 + threadIdx.x;       // 65536 = 1024 j x 64 d
        int j = g >> 6, d = g & 63;
        float w = __expf(-(float)(d & 31) * 0.29710775393471563f);   // ln(10000)/31
        float ang = (float)j * w;
        float v = (d < 32) ? sinf(ang) : cosf(ang);
        int idx = (((j >> 4) << 1) + (d >> 5)) * 512 + (((d >> 3) & 3) * 16 + (j & 15)) * 8 + (d & 7);
        pe2[idx] = (bf16)v;
    } else if (bid < 448) {
        int wb = bid - 256;
        int which = wb >> 6, bidx = wb & 63;
        const float* W = which == 0 ? W0 : which == 1 ? W1 : W2;
        bf16* Wt = which == 0 ? T0 : which == 1 ? T1 : T2;
        int tx = bidx & 7, ty = bidx >> 3;
        int lane = threadIdx.x & 63, w = threadIdx.x >> 6;
        #pragma unroll
        for (int i = 0; i < 16; i++) {
            int k = ty * 64 + w * 16 + i;
            tile[w * 16 + i][lane] = W[k * 512 + tx * 64 + lane];
        }
        __syncthreads();
        #pragma unroll
        for (int i = 0; i < 16; i++) {
            int n = tx * 64 + w * 16 + i;
            Wt[n * 512 + ty * 64 + lane] = (bf16)tile[lane][w * 16 + i];
        }
    } else {
        int i = ((bid - 448) * 256 + threadIdx.x) * 4;
        f32x4 v = ldf4(kin + i);
        int dh = i & 63, hh = (i >> 6) & 7, t = (i >> 9) & 1023, b = i >> 19;
        int bh = (b << 3) + hh;
        bf16x4 o;
        #pragma unroll
        for (int e = 0; e < 4; e++) o[e] = (bf16)v[e];
        int blk = ((bh << 6) + (t >> 4)) * 2 + (dh >> 5);
        int off = (((dh >> 3) & 3) * 16 + (t & 15)) * 8 + (dh & 7);
        *reinterpret_cast<bf16x4*>(kw + blk * 512 + off) = o;
    }
}

// ---------------- merged q+v proj: 64x64/BK32, pre-transposed bf16 W ----------------
// blockIdx.z==0: query -> q_ws (linear [bh][t][dh]); z==1: value -> v_ws (fragment-swizzled V^T)
__global__ __launch_bounds__(256) void proj_qv(const float* __restrict__ Q, const float* __restrict__ V,
                                               const bf16* __restrict__ WtQ, const bf16* __restrict__ WtV,
                                               const float* __restrict__ bq, const float* __restrict__ bv,
                                               bf16* __restrict__ q_ws, bf16* __restrict__ v_ws) {
    __shared__ bf16 As[64][40];
    __shared__ bf16 Bs[64][40];
    int isv = blockIdx.z;
    const float* A = isv ? V : Q;
    const bf16* Wt = isv ? WtV : WtQ;
    const float* bias = isv ? bv : bq;
    int row0 = blockIdx.x * 64, n0 = blockIdx.y * 64;
    int tid = threadIdx.x, lane = tid & 63, w = tid >> 6, lg = lane >> 4, lr = lane & 15;
    int wm = (w >> 1) * 32, wn = (w & 1) * 32;
    f32x4 acc[2][2] = {};
    for (int k0 = 0; k0 < 512; k0 += 32) {
        int r = tid >> 2, kq = (tid & 3) * 8;
        f32x4 a0 = ldf4(A + (row0 + r) * 512 + k0 + kq);
        f32x4 a1 = ldf4(A + (row0 + r) * 512 + k0 + kq + 4);
        bf16x8 av;
        #pragma unroll
        for (int e = 0; e < 4; e++) { av[e] = (bf16)a0[e]; av[4 + e] = (bf16)a1[e]; }
        bf16x8 bv8 = ld8(Wt + (n0 + r) * 512 + k0 + kq);
        __syncthreads();
        *reinterpret_cast<bf16x8*>(&As[r][kq]) = av;
        *reinterpret_cast<bf16x8*>(&Bs[r][kq]) = bv8;
        __syncthreads();
        bf16x8 aa0 = ld8(&As[wm + lr][lg * 8]);
        bf16x8 aa1 = ld8(&As[wm + 16 + lr][lg * 8]);
        bf16x8 bb0 = ld8(&Bs[wn + lr][lg * 8]);
        bf16x8 bb1 = ld8(&Bs[wn + 16 + lr][lg * 8]);
        acc[0][0] = mfma16(aa0, bb0, acc[0][0]);
        acc[0][1] = mfma16(aa0, bb1, acc[0][1]);
        acc[1][0] = mfma16(aa1, bb0, acc[1][0]);
        acc[1][1] = mfma16(aa1, bb1, acc[1][1]);
    }
    #pragma unroll
    for (int mi = 0; mi < 2; mi++)
    #pragma unroll
    for (int ni = 0; ni < 2; ni++) {
        int rowb = row0 + wm + mi * 16 + lg * 4;
        int col = n0 + wn + ni * 16 + lr;
        int b = rowb >> 10, t = rowb & 1023, hh = col >> 6, dh = col & 63;
        int bh = (b << 3) + hh;
        if (isv) {
            int blk = (((bh << 4) + (t >> 6)) * 2 + ((t >> 5) & 1)) * 4 + (dh >> 4);
            int off = (((t >> 3) & 3) * 16 + (dh & 15)) * 8 + (t & 7);
            bf16x4 o4;
            #pragma unroll
            for (int rr = 0; rr < 4; rr++) o4[rr] = (bf16)((float)acc[mi][ni][rr] + bias[col]);
            *reinterpret_cast<bf16x4*>(v_ws + blk * 512 + off) = o4;
        } else {
            #pragma unroll
            for (int rr = 0; rr < 4; rr++) {
                float v = (float)acc[mi][ni][rr] + bias[col];
                q_ws[((bh << 10) + t + rr) * 64 + dh] = (bf16)v;
            }
        }
    }
}

// ---------------- output proj: 64x64/BK32, bf16 A (x_ws), fp32 out ----------------
__global__ __launch_bounds__(256) void proj_o(const bf16* __restrict__ Ap, const bf16* __restrict__ Wt,
                                              const float* __restrict__ bias, float* __restrict__ outp) {
    __shared__ bf16 As[64][40];
    __shared__ bf16 Bs[64][40];
    int row0 = blockIdx.x * 64, n0 = blockIdx.y * 64;
    int tid = threadIdx.x, lane = tid & 63, w = tid >> 6, lg = lane >> 4, lr = lane & 15;
    int wm = (w >> 1) * 32, wn = (w & 1) * 32;
    f32x4 acc[2][2] = {};
    for (int k0 = 0; k0 < 512; k0 += 32) {
        int r = tid >> 2, kq = (tid & 3) * 8;
        bf16x8 av = ld8(Ap + (row0 + r) * 512 + k0 + kq);
        bf16x8 bv = ld8(Wt + (n0 + r) * 512 + k0 + kq);
        __syncthreads();
        *reinterpret_cast<bf16x8*>(&As[r][kq]) = av;
        *reinterpret_cast<bf16x8*>(&Bs[r][kq]) = bv;
        __syncthreads();
        bf16x8 a0 = ld8(&As[wm + lr][lg * 8]);
        bf16x8 a1 = ld8(&As[wm + 16 + lr][lg * 8]);
        bf16x8 b0 = ld8(&Bs[wn + lr][lg * 8]);
        bf16x8 b1 = ld8(&Bs[wn + 16 + lr][lg * 8]);
        acc[0][0] = mfma16(a0, b0, acc[0][0]);
        acc[0][1] = mfma16(a0, b1, acc[0][1]);
        acc[1][0] = mfma16(a1, b0, acc[1][0]);
        acc[1][1] = mfma16(a1, b1, acc[1][1]);
    }
    #pragma unroll
    for (int mi = 0; mi < 2; mi++)
    #pragma unroll
    for (int ni = 0; ni < 2; ni++) {
        int rowb = row0 + wm + mi * 16 + lg * 4;
        int col = n0 + wn + ni * 16 + lr;
        #pragma unroll
        for (int rr = 0; rr < 4; rr++)
            outp[(rowb + rr) * 512 + col] = (float)acc[mi][ni][rr] + bias[col];
    }
}

// ---------------- fused TENER attention: rel folded into augmented QK GEMM ----------------
// grid (64 bh, 32 qt-pairs), block 256 = 4 waves. Logit S[i][j] = q_i.k_j + q2_i.pe2[j],
// q2 built IN-REGISTER in the prologue (RoPE fold of rel+vb).
// Softmax: unconditional rescale (r14 form) — r15's defer-rescale branch regressed
// (skip prob ~(t/(t+1))^16 ~ 0; branches broke scheduler interleave, +4us).
// (256,4) measured-best; tighter bounds or extra live state spills (r5/r10/r12).
__global__ __launch_bounds__(256, 4) void tener_attn(const bf16* __restrict__ qw, const bf16* __restrict__ kw,
                                                     const bf16* __restrict__ vt, const int* __restrict__ mask,
                                                     const bf16* __restrict__ pe2, const float* __restrict__ v_bias,
                                                     bf16* __restrict__ xw) {
    __shared__ bf16 Pl[4][16][76];     // per-wave P relayout
    __shared__ float Mo[4][16], Do[4][16];
    __shared__ float Oo[2][16][65];    // odd-wave partial O per pair
    int bh = blockIdx.x, b = bh >> 3, h = bh & 7;
    int tid = threadIdx.x, w = tid >> 6, lane = tid & 63, lg = lane >> 4, lr = lane & 15;
    int rbase = (blockIdx.y * 2 + (w >> 1)) * 16;
    int jh = w & 1;

    const int* mkb = mask + (b << 10);

    int qoff = ((bh << 10) + rbase + lr) * 64 + lg * 8;
    bf16x8 aq0 = ld8(qw + qoff);
    bf16x8 aq1 = ld8(qw + qoff + 32);

    // build q2 fragments in-register: q2 = R(-t)(q + v_bias[h]).
    bf16x8 aq2, aq3;
    {
        int t = rbase + lr;
        const float* vbp = v_bias + (h << 6) + lg * 8;
        #pragma unroll
        for (int e = 0; e < 8; e++) {
            int d = lg * 8 + e;
            float as = (float)aq0[e] + vbp[e];
            float ac = (float)aq1[e] + vbp[32 + e];
            float w_ = __expf(-(float)d * 0.29710775393471563f);
            float sa, ca;
            __sincosf((float)t * w_, &sa, &ca);
            aq2[e] = (bf16)(as * ca + ac * sa);
            aq3[e] = (bf16)(ac * ca - as * sa);
        }
    }

    f32x4 o[4] = {};
    float m_[4], d_[4];
    #pragma unroll
    for (int r = 0; r < 4; r++) { m_[r] = NEGBIG; d_[r] = 0.f; }

    for (int tt = 0; tt < 8; tt++) {
        __builtin_amdgcn_sched_barrier(0x7F);   // DS may not cross

        int j0 = jh * 512 + tt * 64;

        // S = [q;q2] . [k;pe2]^T — all fragment loads fully coalesced
        f32x4 s[4];
        int kblk = (bh << 6) + (j0 >> 4);
        int pblk = j0 >> 4;
        #pragma unroll
        for (int nt = 0; nt < 4; nt++) {
            const bf16* kp = kw + (((kblk + nt) << 1)) * 512 + lane * 8;
            const bf16* pp = pe2 + (((pblk + nt) << 1)) * 512 + lane * 8;
            f32x4 acc = {};
            acc = mfma16(aq0, ld8(kp), acc);
            acc = mfma16(aq1, ld8(kp + 512), acc);
            acc = mfma16(aq2, ld8(pp), acc);
            acc = mfma16(aq3, ld8(pp + 512), acc);
            s[nt] = acc;
        }

        int mk[4];
        #pragma unroll
        for (int nt = 0; nt < 4; nt++) mk[nt] = mkb[j0 + nt * 16 + lr];

        // online softmax — branch-free unconditional rescale (r14 form)
        #pragma unroll
        for (int r = 0; r < 4; r++) {
            int rl = 4 * lg + r;
            float sv[4];
            #pragma unroll
            for (int nt = 0; nt < 4; nt++) sv[nt] = mk[nt] ? (float)s[nt][r] : NEGBIG;
            float mx = fmaxf(fmaxf(sv[0], sv[1]), fmaxf(sv[2], sv[3]));
            mx = rowmax16(mx);
            float nm = fmaxf(m_[r], mx);
            float sc = __expf(m_[r] - nm);
            float p[4], rs = 0.f;
            #pragma unroll
            for (int nt = 0; nt < 4; nt++) {
                p[nt] = mk[nt] ? __expf(sv[nt] - nm) : 0.f;
                rs += p[nt];
            }
            rs = rowsum16(rs);
            d_[r] = d_[r] * sc + rs;
            m_[r] = nm;
            #pragma unroll
            for (int dt = 0; dt < 4; dt++) o[dt][r] *= sc;
            #pragma unroll
            for (int nt = 0; nt < 4; nt++) Pl[w][rl][nt * 16 + lr] = (bf16)p[nt];
        }

        __builtin_amdgcn_sched_barrier(0x7F);   // DS may not cross (Pl WAR/RAW fence)

        // O += P.V — V^T fragment loads fully coalesced
        int vblk0 = ((((bh << 4) + (j0 >> 6)) << 1)) << 2;
        #pragma unroll
        for (int ks = 0; ks < 2; ks++) {
            bf16x8 ap = ld8(&Pl[w][lr][ks * 32 + lg * 8]);
            #pragma unroll
            for (int dt = 0; dt < 4; dt++) {
                const bf16* vp = vt + (vblk0 + (ks << 2) + dt) * 512 + lane * 8;
                o[dt] = mfma16(ap, ld8(vp), o[dt]);
            }
        }
    }

    // pair-merge: odd wave publishes partials, even wave combines + writes
    if (w & 1) {
        #pragma unroll
        for (int dt = 0; dt < 4; dt++)
        #pragma unroll
        for (int r = 0; r < 4; r++)
            Oo[w >> 1][4 * lg + r][dt * 16 + lr] = o[dt][r];
        if (lr == 0) {
            #pragma unroll
            for (int r = 0; r < 4; r++) { Mo[w][4 * lg + r] = m_[r]; Do[w][4 * lg + r] = d_[r]; }
        }
    }
    __syncthreads();
    if (!(w & 1)) {
        #pragma unroll
        for (int r = 0; r < 4; r++) {
            int rl = 4 * lg + r;
            float m1 = Mo[w | 1][rl], d1 = Do[w | 1][rl];
            float m = fmaxf(m_[r], m1);
            float a0 = __expf(m_[r] - m), a1 = __expf(m1 - m);
            float dd = d_[r] * a0 + d1 * a1;
            float inv = dd > 0.f ? 1.f / dd : 0.f;
            int row = rbase + rl;
            #pragma unroll
            for (int dt = 0; dt < 4; dt++) {
                float v = (o[dt][r] * a0 + Oo[w >> 1][rl][dt * 16 + lr] * a1) * inv;
                xw[(((b << 10) + row) << 9) + (h << 6) + dt * 16 + lr] = (bf16)v;
            }
        }
    }
}

extern "C" void kernel_launch(void* const* d_in, const int* in_sizes, int n_in,
                              void* d_out, int out_size, void* d_ws, size_t ws_size,
                              hipStream_t stream) {
    const float* query  = (const float*)d_in[0];
    const float* key_in = (const float*)d_in[1];
    const float* value  = (const float*)d_in[2];
    const int*   mask   = (const int*)d_in[3];
    const float* Wq     = (const float*)d_in[4];
    const float* bq     = (const float*)d_in[5];
    const float* Wv     = (const float*)d_in[6];
    const float* bv     = (const float*)d_in[7];
    const float* Wo     = (const float*)d_in[8];
    const float* bo     = (const float*)d_in[9];
    const float* v_bias = (const float*)d_in[10];

    char* ws = (char*)d_ws;
    bf16*  pe2  = (bf16*)(ws);                           // 128 KB (swizzled, pos=j)
    bf16*  q_ws = (bf16*)(ws + 327680);                  // 8 MB  [bh][t][dh]
    bf16*  v_ws = (bf16*)(ws + 327680 + 8388608);        // 8 MB  V^T fragment-swizzled
    bf16*  x_ws = (bf16*)(ws + 327680 + 16777216);       // 8 MB  [b*t][512]
    bf16*  wt_q = (bf16*)(ws + 327680 + 25165824);       // 512 KB  Wq^T bf16
    bf16*  wt_v = (bf16*)(ws + 327680 + 25690112);       // 512 KB  Wv^T bf16
    bf16*  wt_o = (bf16*)(ws + 327680 + 26214400);       // 512 KB  Wo^T bf16
    // k_ws lives in d_out's first 8 MB; fully consumed by tener_attn before
    // proj_o overwrites d_out.
    bf16*  k_ws = (bf16*)d_out;

    tables_kernel<<<4544, 256, 0, stream>>>(Wq, Wv, Wo, key_in, pe2, wt_q, wt_v, wt_o, k_ws);
    proj_qv<<<dim3(128, 8, 2), 256, 0, stream>>>(query, value, wt_q, wt_v, bq, bv, q_ws, v_ws);
    tener_attn<<<dim3(64, 32), 256, 0, stream>>>(q_ws, k_ws, v_ws, mask, pe2, v_bias, x_ws);
    proj_o<<<dim3(128, 8), 256, 0, stream>>>(x_ws, wt_o, bo, (float*)d_out);
}